// Round 1
// baseline (943.466 us; speedup 1.0000x reference)
//
#include <hip/hip_runtime.h>

#define D 256
#define NH 8
#define DH 32
#define NL 4
#define NP 4
#define DFF 1024
#define LTOT 8500

// ---------------- elementwise add ----------------
__global__ void add_vec(const float* __restrict__ a, const float* __restrict__ b,
                        float* __restrict__ c, int n) {
    int i = blockIdx.x * blockDim.x + threadIdx.x;
    if (i < n) c[i] = a[i] + b[i];
}

// ---------------- fp32 tiled GEMM: C[M,N] = A[M,K] @ B[K,N] + bias ----------------
// 32x32 tile, 256 threads, 4 outputs/thread. N,K multiples of 32; M ragged.
__global__ void gemm_bias(const float* __restrict__ A, const float* __restrict__ B,
                          const float* __restrict__ bias, float* __restrict__ C,
                          int M, int N, int K, int relu) {
    __shared__ float As[32][33];
    __shared__ float Bs[32][33];
    int tid = threadIdx.x;
    int tx = tid & 31;       // col within tile
    int ty = tid >> 5;       // 0..7
    int n0 = blockIdx.x * 32;
    int m0 = blockIdx.y * 32;
    float acc[4] = {0.f, 0.f, 0.f, 0.f};

    for (int k0 = 0; k0 < K; k0 += 32) {
#pragma unroll
        for (int i = 0; i < 4; i++) {
            int e = tid + 256 * i;
            int r = e >> 5, c = e & 31;
            int row = m0 + r;
            As[r][c] = (row < M) ? A[row * K + k0 + c] : 0.f;
            Bs[r][c] = B[(k0 + r) * N + n0 + c];
        }
        __syncthreads();
#pragma unroll
        for (int k = 0; k < 32; k++) {
            float bv = Bs[k][tx];
#pragma unroll
            for (int r = 0; r < 4; r++)
                acc[r] += As[ty + 8 * r][k] * bv;
        }
        __syncthreads();
    }
    float bb = bias[n0 + tx];
#pragma unroll
    for (int r = 0; r < 4; r++) {
        int row = m0 + ty + 8 * r;
        if (row < M) {
            float v = acc[r] + bb;
            if (relu) v = fmaxf(v, 0.f);
            C[row * N + n0 + tx] = v;
        }
    }
}

// ---------------- softmax over 16 logits + sampling-location computation ----------------
// one thread per (query, head). attn in-place logits -> weights. loc in-place off -> loc.
__global__ void softmax_loc(const float* __restrict__ refp, float* __restrict__ attn,
                            float* __restrict__ loc) {
    int g = blockIdx.x * blockDim.x + threadIdx.x;
    if (g >= LTOT * NH) return;
    int q = g >> 3, h = g & 7;

    float* lg = attn + q * (NH * NL * NP) + h * (NL * NP);
    float v[16];
    float mx = -1e30f;
#pragma unroll
    for (int j = 0; j < 16; j++) { v[j] = lg[j]; mx = fmaxf(mx, v[j]); }
    float s = 0.f;
#pragma unroll
    for (int j = 0; j < 16; j++) { v[j] = __expf(v[j] - mx); s += v[j]; }
    float inv = 1.f / s;
#pragma unroll
    for (int j = 0; j < 16; j++) lg[j] = v[j] * inv;

    float* lc = loc + q * 256 + h * 32;
#pragma unroll
    for (int l = 0; l < 4; l++) {
        float nv = (float)(80 >> l);   // 80,40,20,10 (square levels: W==H)
        float rx = refp[(q * 4 + l) * 2 + 0];
        float ry = refp[(q * 4 + l) * 2 + 1];
#pragma unroll
        for (int p = 0; p < 4; p++) {
            int o = (l * 4 + p) * 2;
            lc[o + 0] = rx + lc[o + 0] / nv;
            lc[o + 1] = ry + lc[o + 1] / nv;
        }
    }
}

// ---------------- multi-scale deformable attention core ----------------
// 32-lane group per (query, head); lane = channel. Coalesced 128B value gathers.
__global__ void deform(const float* __restrict__ value, const float* __restrict__ loc,
                       const float* __restrict__ attn, float* __restrict__ out) {
    int g = blockIdx.x * 8 + (threadIdx.x >> 5);
    if (g >= LTOT * NH) return;
    int lane = threadIdx.x & 31;
    int q = g >> 3, h = g & 7;

    const float* lc = loc + q * 256 + h * 32;
    const float* aw = attn + q * 128 + h * 16;
    const int starts[4] = {0, 6400, 8000, 8400};

    float acc = 0.f;
#pragma unroll
    for (int l = 0; l < 4; l++) {
        int Wl = 80 >> l;
        int Hl = 80 >> l;
        int st = starts[l];
#pragma unroll
        for (int p = 0; p < 4; p++) {
            float lx = lc[(l * 4 + p) * 2 + 0];
            float ly = lc[(l * 4 + p) * 2 + 1];
            float x = lx * (float)Wl - 0.5f;
            float y = ly * (float)Hl - 0.5f;
            float x0 = floorf(x), y0 = floorf(y);
            float a = aw[l * 4 + p];
            float s = 0.f;
#pragma unroll
            for (int dy = 0; dy < 2; dy++) {
#pragma unroll
                for (int dx = 0; dx < 2; dx++) {
                    float xi = x0 + dx, yi = y0 + dy;
                    float w = (1.f - fabsf(x - xi)) * (1.f - fabsf(y - yi));
                    bool valid = (xi >= 0.f) & (xi < (float)Wl) & (yi >= 0.f) & (yi < (float)Hl);
                    if (valid) {
                        int xic = (int)xi, yic = (int)yi;
                        s += w * value[(size_t)(st + yic * Wl + xic) * 256 + h * 32 + lane];
                    }
                }
            }
            acc += a * s;
        }
    }
    out[q * 256 + h * 32 + lane] = acc;
}

// ---------------- layernorm(a+b) * g + be, one block (256 thr) per row ----------------
__global__ void layernorm(const float* __restrict__ a, const float* __restrict__ b,
                          const float* __restrict__ g, const float* __restrict__ be,
                          float* __restrict__ out) {
    int q = blockIdx.x;
    int c = threadIdx.x;   // 256 threads = 4 waves
    float v = a[q * 256 + c] + b[q * 256 + c];

    __shared__ float red[4];
    float s = v;
#pragma unroll
    for (int o = 32; o > 0; o >>= 1) s += __shfl_down(s, o, 64);
    if ((c & 63) == 0) red[c >> 6] = s;
    __syncthreads();
    float m = (red[0] + red[1] + red[2] + red[3]) * (1.f / 256.f);
    __syncthreads();

    float d = v - m;
    s = d * d;
#pragma unroll
    for (int o = 32; o > 0; o >>= 1) s += __shfl_down(s, o, 64);
    if ((c & 63) == 0) red[c >> 6] = s;
    __syncthreads();
    float var = (red[0] + red[1] + red[2] + red[3]) * (1.f / 256.f);
    float r = rsqrtf(var + 1e-5f);
    out[q * 256 + c] = d * r * g[c] + be[c];
}

extern "C" void kernel_launch(void* const* d_in, const int* in_sizes, int n_in,
                              void* d_out, int out_size, void* d_ws, size_t ws_size,
                              hipStream_t stream) {
    const float* src  = (const float*)d_in[0];
    const float* pos  = (const float*)d_in[1];
    const float* refp = (const float*)d_in[2];
    // d_in[3] spatial_shapes, d_in[4] level_start_index, d_in[5] scale: compile-time constants
    const float* Wo   = (const float*)d_in[6];
    const float* bo   = (const float*)d_in[7];
    const float* Wa   = (const float*)d_in[8];
    const float* ba   = (const float*)d_in[9];
    const float* Wv   = (const float*)d_in[10];
    const float* bv   = (const float*)d_in[11];
    const float* Wout = (const float*)d_in[12];
    const float* bout = (const float*)d_in[13];
    const float* W1   = (const float*)d_in[14];
    const float* b1   = (const float*)d_in[15];
    const float* W2   = (const float*)d_in[16];
    const float* b2   = (const float*)d_in[17];
    const float* g1   = (const float*)d_in[18];
    const float* be1  = (const float*)d_in[19];
    const float* g2   = (const float*)d_in[20];
    const float* be2  = (const float*)d_in[21];
    float* out = (float*)d_out;
    float* ws  = (float*)d_ws;

    // workspace layout (floats), liveness-based reuse. total = 14,144,000 floats (~56.6 MB)
    float* qb    = ws + 0;          // 2,176,000  (dead after off/attn GEMMs)
    float* locb  = ws + 2176000;    // 2,176,000  off -> loc
    float* attnb = ws + 4352000;    // 1,088,000  logits -> weights
    float* valb  = ws + 5440000;    // 2,176,000  value
    float* aob   = ws + 7616000;    // 2,176,000  deform output
    float* src2  = ws + 0;          // reuse qb
    float* x1    = ws + 9792000;    // 2,176,000
    float* hb    = ws + 0;          // 8,704,000  reuses [0..8704000) (all dead by then)
    float* ffnb  = ws + 11968000;   // 2,176,000

    int n = LTOT * D;
    dim3 blk(256);

    add_vec<<<(n + 255) / 256, 256, 0, stream>>>(src, pos, qb, n);
    gemm_bias<<<dim3(256 / 32, 266), blk, 0, stream>>>(qb, Wo, bo, locb, LTOT, 256, 256, 0);
    gemm_bias<<<dim3(128 / 32, 266), blk, 0, stream>>>(qb, Wa, ba, attnb, LTOT, 128, 256, 0);
    gemm_bias<<<dim3(256 / 32, 266), blk, 0, stream>>>(src, Wv, bv, valb, LTOT, 256, 256, 0);
    softmax_loc<<<(LTOT * NH + 255) / 256, 256, 0, stream>>>(refp, attnb, locb);
    deform<<<LTOT, 256, 0, stream>>>(valb, locb, attnb, aob);
    gemm_bias<<<dim3(256 / 32, 266), blk, 0, stream>>>(aob, Wout, bout, src2, LTOT, 256, 256, 0);
    layernorm<<<LTOT, 256, 0, stream>>>(src, src2, g1, be1, x1);
    gemm_bias<<<dim3(1024 / 32, 266), blk, 0, stream>>>(x1, W1, b1, hb, LTOT, 1024, 256, 1);
    gemm_bias<<<dim3(256 / 32, 266), blk, 0, stream>>>(hb, W2, b2, ffnb, LTOT, 256, 1024, 0);
    layernorm<<<LTOT, 256, 0, stream>>>(x1, ffnb, g2, be2, out);
}

// Round 2
// 332.462 us; speedup vs baseline: 2.8378x; 2.8378x over previous
//
#include <hip/hip_runtime.h>
#include <hip/hip_bf16.h>

#define D 256
#define NH 8
#define DH 32
#define NL 4
#define NP 4
#define DFF 1024
#define LTOT 8500

typedef __bf16 bf16x8 __attribute__((ext_vector_type(8)));
typedef float floatx4 __attribute__((ext_vector_type(4)));

// ---------------- prep: qb = bf16(src+pos), srcb = bf16(src) ----------------
__global__ void prep(const float* __restrict__ src, const float* __restrict__ pos,
                     __hip_bfloat16* __restrict__ qb, __hip_bfloat16* __restrict__ srcb, int n) {
    int i = blockIdx.x * blockDim.x + threadIdx.x;
    if (i < n) {
        float s = src[i];
        srcb[i] = __float2bfloat16(s);
        qb[i] = __float2bfloat16(s + pos[i]);
    }
}

// ---------------- transpose+convert all 6 weights: W[K][N] fp32 -> WT[N][K] bf16 ----------------
__global__ void transpose_all(const float* W0, const float* W1_, const float* W2_,
                              const float* W3, const float* W4, const float* W5,
                              __hip_bfloat16* T0, __hip_bfloat16* T1, __hip_bfloat16* T2,
                              __hip_bfloat16* T3, __hip_bfloat16* T4, __hip_bfloat16* T5) {
    const float* W; __hip_bfloat16* T; int K, N;
    switch (blockIdx.z) {
        case 0: W = W0; T = T0; K = 256;  N = 256;  break; // Wo
        case 1: W = W1_; T = T1; K = 256; N = 128;  break; // Wa
        case 2: W = W2_; T = T2; K = 256; N = 256;  break; // Wv
        case 3: W = W3; T = T3; K = 256;  N = 256;  break; // Wout
        case 4: W = W4; T = T4; K = 256;  N = 1024; break; // W1
        default: W = W5; T = T5; K = 1024; N = 256; break; // W2
    }
    int bx = blockIdx.x, by = blockIdx.y;
    if (bx >= (N >> 5) || by >= (K >> 5)) return;
    __shared__ float t[32][33];
    int n0 = bx * 32, k0 = by * 32;
    int tx = threadIdx.x & 31, ty = threadIdx.x >> 5; // 256 thr: ty 0..7
#pragma unroll
    for (int i = 0; i < 32; i += 8)
        t[ty + i][tx] = W[(size_t)(k0 + ty + i) * N + n0 + tx];
    __syncthreads();
#pragma unroll
    for (int i = 0; i < 32; i += 8)
        T[(size_t)(n0 + ty + i) * K + k0 + tx] = __float2bfloat16(t[tx][ty + i]);
}

// ---------------- bf16 MFMA GEMM: C[M,N] = A[M,K] @ W[K,N] + bias ----------------
// A row-major bf16 [M][K]; BT = W^T row-major bf16 [N][K]. 4 waves in 2x2 grid.
template<int BM, int BN>
__global__ __launch_bounds__(256) void gemm_mfma(
    const __hip_bfloat16* __restrict__ A, const __hip_bfloat16* __restrict__ BT,
    const float* __restrict__ bias, float* __restrict__ Cf, __hip_bfloat16* __restrict__ Cb,
    int M, int N, int K, int relu) {
    constexpr int BK = 32;
    constexpr int LDA = BK + 8;           // pad to 40 elems (80 B): 16B-aligned, 2-way-max banks
    __shared__ __hip_bfloat16 sA[BM * LDA];
    __shared__ __hip_bfloat16 sB[BN * LDA];

    int tid = threadIdx.x;
    int wave = tid >> 6, lane = tid & 63;
    int m0 = blockIdx.y * BM;
    int n0 = blockIdx.x * BN;
    constexpr int WM = BM / 2, WN = BN / 2;
    int wm = (wave >> 1) * WM;
    int wn = (wave & 1) * WN;
    constexpr int TM = WM / 16, TN = WN / 16;

    floatx4 acc[TM][TN];
#pragma unroll
    for (int i = 0; i < TM; i++)
#pragma unroll
        for (int j = 0; j < TN; j++)
#pragma unroll
            for (int e = 0; e < 4; e++) acc[i][j][e] = 0.f;

    // staging map: each thread moves one 16B chunk per 64-row round
    constexpr int RA = BM / 64, RB = BN / 64;
    int rowT = tid >> 2;        // 0..63
    int c16 = tid & 3;          // which 16B chunk of the 64B (32 bf16) row

    int lrow = lane & 15;
    int lk = (lane >> 4) * 8;

    for (int k0 = 0; k0 < K; k0 += BK) {
#pragma unroll
        for (int r = 0; r < RA; r++) {
            int row = r * 64 + rowT;
            int grow = m0 + row; if (grow >= M) grow = M - 1;   // clamp: junk rows never stored
            bf16x8 v = *(const bf16x8*)(A + (size_t)grow * K + k0 + c16 * 8);
            *(bf16x8*)(&sA[row * LDA + c16 * 8]) = v;
        }
#pragma unroll
        for (int r = 0; r < RB; r++) {
            int row = r * 64 + rowT;
            bf16x8 v = *(const bf16x8*)(BT + (size_t)(n0 + row) * K + k0 + c16 * 8);
            *(bf16x8*)(&sB[row * LDA + c16 * 8]) = v;
        }
        __syncthreads();

        bf16x8 af[TM], bf[TN];
#pragma unroll
        for (int tm = 0; tm < TM; tm++)
            af[tm] = *(const bf16x8*)(&sA[(wm + tm * 16 + lrow) * LDA + lk]);
#pragma unroll
        for (int tn = 0; tn < TN; tn++)
            bf[tn] = *(const bf16x8*)(&sB[(wn + tn * 16 + lrow) * LDA + lk]);
#pragma unroll
        for (int tm = 0; tm < TM; tm++)
#pragma unroll
            for (int tn = 0; tn < TN; tn++)
                acc[tm][tn] = __builtin_amdgcn_mfma_f32_16x16x32_bf16(af[tm], bf[tn], acc[tm][tn], 0, 0, 0);
        __syncthreads();
    }

    int lcol = lane & 15;
    int lr4 = (lane >> 4) * 4;
#pragma unroll
    for (int tm = 0; tm < TM; tm++) {
#pragma unroll
        for (int i = 0; i < 4; i++) {
            int row = m0 + wm + tm * 16 + lr4 + i;
            if (row < M) {
#pragma unroll
                for (int tn = 0; tn < TN; tn++) {
                    int col = n0 + wn + tn * 16 + lcol;
                    float v = acc[tm][tn][i] + bias[col];
                    if (relu) v = fmaxf(v, 0.f);
                    if (Cf) Cf[(size_t)row * N + col] = v;
                    if (Cb) Cb[(size_t)row * N + col] = __float2bfloat16(v);
                }
            }
        }
    }
}

// ---------------- softmax over 16 logits + sampling-location computation ----------------
__global__ void softmax_loc(const float* __restrict__ refp, float* __restrict__ attn,
                            float* __restrict__ loc) {
    int g = blockIdx.x * blockDim.x + threadIdx.x;
    if (g >= LTOT * NH) return;
    int q = g >> 3, h = g & 7;

    float* lg = attn + q * (NH * NL * NP) + h * (NL * NP);
    float v[16];
    float mx = -1e30f;
#pragma unroll
    for (int j = 0; j < 16; j++) { v[j] = lg[j]; mx = fmaxf(mx, v[j]); }
    float s = 0.f;
#pragma unroll
    for (int j = 0; j < 16; j++) { v[j] = __expf(v[j] - mx); s += v[j]; }
    float inv = 1.f / s;
#pragma unroll
    for (int j = 0; j < 16; j++) lg[j] = v[j] * inv;

    float* lc = loc + q * 256 + h * 32;
#pragma unroll
    for (int l = 0; l < 4; l++) {
        float nv = (float)(80 >> l);
        float rx = refp[(q * 4 + l) * 2 + 0];
        float ry = refp[(q * 4 + l) * 2 + 1];
#pragma unroll
        for (int p = 0; p < 4; p++) {
            int o = (l * 4 + p) * 2;
            lc[o + 0] = rx + lc[o + 0] / nv;
            lc[o + 1] = ry + lc[o + 1] / nv;
        }
    }
}

// ---------------- multi-scale deformable attention core ----------------
__global__ void deform(const float* __restrict__ value, const float* __restrict__ loc,
                       const float* __restrict__ attn, __hip_bfloat16* __restrict__ out) {
    int g = blockIdx.x * 8 + (threadIdx.x >> 5);
    if (g >= LTOT * NH) return;
    int lane = threadIdx.x & 31;
    int q = g >> 3, h = g & 7;

    const float* lc = loc + q * 256 + h * 32;
    const float* aw = attn + q * 128 + h * 16;
    const int starts[4] = {0, 6400, 8000, 8400};

    float acc = 0.f;
#pragma unroll
    for (int l = 0; l < 4; l++) {
        int Wl = 80 >> l;
        int Hl = 80 >> l;
        int st = starts[l];
#pragma unroll
        for (int p = 0; p < 4; p++) {
            float lx = lc[(l * 4 + p) * 2 + 0];
            float ly = lc[(l * 4 + p) * 2 + 1];
            float x = lx * (float)Wl - 0.5f;
            float y = ly * (float)Hl - 0.5f;
            float x0 = floorf(x), y0 = floorf(y);
            float a = aw[l * 4 + p];
            float s = 0.f;
#pragma unroll
            for (int dy = 0; dy < 2; dy++) {
#pragma unroll
                for (int dx = 0; dx < 2; dx++) {
                    float xi = x0 + dx, yi = y0 + dy;
                    float w = (1.f - fabsf(x - xi)) * (1.f - fabsf(y - yi));
                    bool valid = (xi >= 0.f) & (xi < (float)Wl) & (yi >= 0.f) & (yi < (float)Hl);
                    if (valid) {
                        int xic = (int)xi, yic = (int)yi;
                        s += w * value[(size_t)(st + yic * Wl + xic) * 256 + h * 32 + lane];
                    }
                }
            }
            acc += a * s;
        }
    }
    out[q * 256 + h * 32 + lane] = __float2bfloat16(acc);
}

// ---------------- layernorm(a+b)*g+be; optional bf16 second output ----------------
__global__ void layernorm(const float* __restrict__ a, const float* __restrict__ b,
                          const float* __restrict__ g, const float* __restrict__ be,
                          float* __restrict__ outf, __hip_bfloat16* __restrict__ outb) {
    int q = blockIdx.x;
    int c = threadIdx.x;
    float v = a[q * 256 + c] + b[q * 256 + c];

    __shared__ float red[4];
    float s = v;
#pragma unroll
    for (int o = 32; o > 0; o >>= 1) s += __shfl_down(s, o, 64);
    if ((c & 63) == 0) red[c >> 6] = s;
    __syncthreads();
    float m = (red[0] + red[1] + red[2] + red[3]) * (1.f / 256.f);
    __syncthreads();

    float d = v - m;
    s = d * d;
#pragma unroll
    for (int o = 32; o > 0; o >>= 1) s += __shfl_down(s, o, 64);
    if ((c & 63) == 0) red[c >> 6] = s;
    __syncthreads();
    float var = (red[0] + red[1] + red[2] + red[3]) * (1.f / 256.f);
    float r = rsqrtf(var + 1e-5f);
    float o = d * r * g[c] + be[c];
    outf[q * 256 + c] = o;
    if (outb) outb[q * 256 + c] = __float2bfloat16(o);
}

extern "C" void kernel_launch(void* const* d_in, const int* in_sizes, int n_in,
                              void* d_out, int out_size, void* d_ws, size_t ws_size,
                              hipStream_t stream) {
    const float* src  = (const float*)d_in[0];
    const float* pos  = (const float*)d_in[1];
    const float* refp = (const float*)d_in[2];
    const float* Wo   = (const float*)d_in[6];
    const float* bo   = (const float*)d_in[7];
    const float* Wa   = (const float*)d_in[8];
    const float* ba   = (const float*)d_in[9];
    const float* Wv   = (const float*)d_in[10];
    const float* bv   = (const float*)d_in[11];
    const float* Wout = (const float*)d_in[12];
    const float* bout = (const float*)d_in[13];
    const float* W1   = (const float*)d_in[14];
    const float* b1   = (const float*)d_in[15];
    const float* W2   = (const float*)d_in[16];
    const float* b2   = (const float*)d_in[17];
    const float* g1   = (const float*)d_in[18];
    const float* be1  = (const float*)d_in[19];
    const float* g2   = (const float*)d_in[20];
    const float* be2  = (const float*)d_in[21];
    float* out = (float*)d_out;
    char* ws = (char*)d_ws;

    // ---- workspace layout (bytes), liveness-reused; total ~49.4 MB ----
    __hip_bfloat16* WoT   = (__hip_bfloat16*)(ws + 0);         // 256x256  bf16 = 131072
    __hip_bfloat16* WaT   = (__hip_bfloat16*)(ws + 131072);    // 128x256           65536
    __hip_bfloat16* WvT   = (__hip_bfloat16*)(ws + 196608);    // 256x256          131072
    __hip_bfloat16* WoutT = (__hip_bfloat16*)(ws + 327680);    // 256x256          131072
    __hip_bfloat16* W1T   = (__hip_bfloat16*)(ws + 458752);    // 1024x256         524288
    __hip_bfloat16* W2T   = (__hip_bfloat16*)(ws + 983040);    // 256x1024         524288
    __hip_bfloat16* qb    = (__hip_bfloat16*)(ws + 1507328);   // 8500x256 bf16   4352000
    __hip_bfloat16* srcb  = (__hip_bfloat16*)(ws + 5859328);   // 8500x256 bf16   4352000
    float*          locb  = (float*)(ws + 10211328);           // 8500x256 f32    8704000
    float*          attnb = (float*)(ws + 18915328);           // 8500x128 f32    4352000
    float*          valb  = (float*)(ws + 23267328);           // 8500x256 f32    8704000
    __hip_bfloat16* hb    = (__hip_bfloat16*)(ws + 31971328);  // 8500x1024 bf16 17408000 (+slack after)
    // reuse (liveness-disjoint):
    __hip_bfloat16* aob  = qb;                                  // after qb dead
    float*          src2 = valb;                                // after valb dead
    float*          x1   = locb;                                // after locb dead
    __hip_bfloat16* x1b  = srcb;                                // after srcb dead
    float*          ffnb = valb;                                // after src2 dead

    int n = LTOT * D;
    prep<<<(n + 255) / 256, 256, 0, stream>>>(src, pos, qb, srcb, n);
    transpose_all<<<dim3(32, 32, 6), 256, 0, stream>>>(Wo, Wa, Wv, Wout, W1, W2,
                                                       WoT, WaT, WvT, WoutT, W1T, W2T);

    gemm_mfma<64, 128><<<dim3(2, 133), 256, 0, stream>>>(qb, WoT, bo, locb, nullptr, LTOT, 256, 256, 0);
    gemm_mfma<64, 64><<<dim3(2, 133), 256, 0, stream>>>(qb, WaT, ba, attnb, nullptr, LTOT, 128, 256, 0);
    gemm_mfma<64, 128><<<dim3(2, 133), 256, 0, stream>>>(srcb, WvT, bv, valb, nullptr, LTOT, 256, 256, 0);

    softmax_loc<<<(LTOT * NH + 255) / 256, 256, 0, stream>>>(refp, attnb, locb);
    deform<<<LTOT, 256, 0, stream>>>(valb, locb, attnb, aob);

    gemm_mfma<64, 128><<<dim3(2, 133), 256, 0, stream>>>(aob, WoutT, bout, src2, nullptr, LTOT, 256, 256, 0);
    layernorm<<<LTOT, 256, 0, stream>>>(src, src2, g1, be1, x1, x1b);
    gemm_mfma<128, 128><<<dim3(8, 67), 256, 0, stream>>>(x1b, W1T, b1, nullptr, hb, LTOT, 1024, 256, 1);
    gemm_mfma<64, 128><<<dim3(2, 133), 256, 0, stream>>>(hb, W2T, b2, ffnb, nullptr, LTOT, 256, 1024, 0);
    layernorm<<<LTOT, 256, 0, stream>>>(x1, ffnb, g2, be2, out, nullptr);
}

// Round 3
// 289.942 us; speedup vs baseline: 3.2540x; 1.1466x over previous
//
#include <hip/hip_runtime.h>
#include <hip/hip_bf16.h>

#define D 256
#define NH 8
#define DH 32
#define NL 4
#define NP 4
#define DFF 1024
#define LTOT 8500

typedef __bf16 bf16x8 __attribute__((ext_vector_type(8)));
typedef float floatx4 __attribute__((ext_vector_type(4)));

// ---------------- prep: qb = bf16(src+pos), srcb = bf16(src) ----------------
__global__ void prep(const float* __restrict__ src, const float* __restrict__ pos,
                     __hip_bfloat16* __restrict__ qb, __hip_bfloat16* __restrict__ srcb, int n) {
    int i = blockIdx.x * blockDim.x + threadIdx.x;
    if (i < n) {
        float s = src[i];
        srcb[i] = __float2bfloat16(s);
        qb[i] = __float2bfloat16(s + pos[i]);
    }
}

// ---------------- transpose+convert all 6 weights: W[K][N] fp32 -> WT[N][K] bf16 ----------------
__global__ void transpose_all(const float* W0, const float* W1_, const float* W2_,
                              const float* W3, const float* W4, const float* W5,
                              __hip_bfloat16* T0, __hip_bfloat16* T1, __hip_bfloat16* T2,
                              __hip_bfloat16* T3, __hip_bfloat16* T4, __hip_bfloat16* T5) {
    const float* W; __hip_bfloat16* T; int K, N;
    switch (blockIdx.z) {
        case 0: W = W0; T = T0; K = 256;  N = 256;  break; // Wo
        case 1: W = W1_; T = T1; K = 256; N = 128;  break; // Wa
        case 2: W = W2_; T = T2; K = 256; N = 256;  break; // Wv
        case 3: W = W3; T = T3; K = 256;  N = 256;  break; // Wout
        case 4: W = W4; T = T4; K = 256;  N = 1024; break; // W1
        default: W = W5; T = T5; K = 1024; N = 256; break; // W2
    }
    int bx = blockIdx.x, by = blockIdx.y;
    if (bx >= (N >> 5) || by >= (K >> 5)) return;
    __shared__ float t[32][33];
    int n0 = bx * 32, k0 = by * 32;
    int tx = threadIdx.x & 31, ty = threadIdx.x >> 5; // 256 thr: ty 0..7
#pragma unroll
    for (int i = 0; i < 32; i += 8)
        t[ty + i][tx] = W[(size_t)(k0 + ty + i) * N + n0 + tx];
    __syncthreads();
#pragma unroll
    for (int i = 0; i < 32; i += 8)
        T[(size_t)(n0 + ty + i) * K + k0 + tx] = __float2bfloat16(t[tx][ty + i]);
}

// ---------------- bf16 MFMA GEMM: C[M,N] = A[M,K] @ W[K,N] + bias ----------------
// A row-major bf16 [M][K]; BT = W^T row-major bf16 [N][K]. 4 waves in 2x2 grid.
template<int BM, int BN>
__global__ __launch_bounds__(256) void gemm_mfma(
    const __hip_bfloat16* __restrict__ A, const __hip_bfloat16* __restrict__ BT,
    const float* __restrict__ bias, float* __restrict__ Cf, __hip_bfloat16* __restrict__ Cb,
    int M, int N, int K, int relu) {
    constexpr int BK = 32;
    constexpr int LDA = BK + 8;           // pad to 40 elems (80 B): 16B-aligned, 2-way-max banks
    __shared__ __hip_bfloat16 sA[BM * LDA];
    __shared__ __hip_bfloat16 sB[BN * LDA];

    int tid = threadIdx.x;
    int wave = tid >> 6, lane = tid & 63;
    int m0 = blockIdx.y * BM;
    int n0 = blockIdx.x * BN;
    constexpr int WM = BM / 2, WN = BN / 2;
    int wm = (wave >> 1) * WM;
    int wn = (wave & 1) * WN;
    constexpr int TM = WM / 16, TN = WN / 16;

    floatx4 acc[TM][TN];
#pragma unroll
    for (int i = 0; i < TM; i++)
#pragma unroll
        for (int j = 0; j < TN; j++)
#pragma unroll
            for (int e = 0; e < 4; e++) acc[i][j][e] = 0.f;

    constexpr int RA = BM / 64, RB = BN / 64;
    int rowT = tid >> 2;        // 0..63
    int c16 = tid & 3;          // which 16B chunk of the 64B (32 bf16) row

    int lrow = lane & 15;
    int lk = (lane >> 4) * 8;

    for (int k0 = 0; k0 < K; k0 += BK) {
#pragma unroll
        for (int r = 0; r < RA; r++) {
            int row = r * 64 + rowT;
            int grow = m0 + row; if (grow >= M) grow = M - 1;   // clamp: junk rows never stored
            bf16x8 v = *(const bf16x8*)(A + (size_t)grow * K + k0 + c16 * 8);
            *(bf16x8*)(&sA[row * LDA + c16 * 8]) = v;
        }
#pragma unroll
        for (int r = 0; r < RB; r++) {
            int row = r * 64 + rowT;
            bf16x8 v = *(const bf16x8*)(BT + (size_t)(n0 + row) * K + k0 + c16 * 8);
            *(bf16x8*)(&sB[row * LDA + c16 * 8]) = v;
        }
        __syncthreads();

        bf16x8 af[TM], bf[TN];
#pragma unroll
        for (int tm = 0; tm < TM; tm++)
            af[tm] = *(const bf16x8*)(&sA[(wm + tm * 16 + lrow) * LDA + lk]);
#pragma unroll
        for (int tn = 0; tn < TN; tn++)
            bf[tn] = *(const bf16x8*)(&sB[(wn + tn * 16 + lrow) * LDA + lk]);
#pragma unroll
        for (int tm = 0; tm < TM; tm++)
#pragma unroll
            for (int tn = 0; tn < TN; tn++)
                acc[tm][tn] = __builtin_amdgcn_mfma_f32_16x16x32_bf16(af[tm], bf[tn], acc[tm][tn], 0, 0, 0);
        __syncthreads();
    }

    int lcol = lane & 15;
    int lr4 = (lane >> 4) * 4;
#pragma unroll
    for (int tm = 0; tm < TM; tm++) {
#pragma unroll
        for (int i = 0; i < 4; i++) {
            int row = m0 + wm + tm * 16 + lr4 + i;
            if (row < M) {
#pragma unroll
                for (int tn = 0; tn < TN; tn++) {
                    int col = n0 + wn + tn * 16 + lcol;
                    float v = acc[tm][tn][i] + bias[col];
                    if (relu) v = fmaxf(v, 0.f);
                    if (Cf) Cf[(size_t)row * N + col] = v;
                    if (Cb) Cb[(size_t)row * N + col] = __float2bfloat16(v);
                }
            }
        }
    }
}

// ---------------- softmax over 16 logits + sampling-location computation ----------------
__global__ void softmax_loc(const float* __restrict__ refp, float* __restrict__ attn,
                            float* __restrict__ loc) {
    int g = blockIdx.x * blockDim.x + threadIdx.x;
    if (g >= LTOT * NH) return;
    int q = g >> 3, h = g & 7;

    float* lg = attn + q * (NH * NL * NP) + h * (NL * NP);
    float v[16];
    float mx = -1e30f;
#pragma unroll
    for (int j = 0; j < 16; j++) { v[j] = lg[j]; mx = fmaxf(mx, v[j]); }
    float s = 0.f;
#pragma unroll
    for (int j = 0; j < 16; j++) { v[j] = __expf(v[j] - mx); s += v[j]; }
    float inv = 1.f / s;
#pragma unroll
    for (int j = 0; j < 16; j++) lg[j] = v[j] * inv;

    float* lc = loc + q * 256 + h * 32;
#pragma unroll
    for (int l = 0; l < 4; l++) {
        float nv = (float)(80 >> l);
        float rx = refp[(q * 4 + l) * 2 + 0];
        float ry = refp[(q * 4 + l) * 2 + 1];
#pragma unroll
        for (int p = 0; p < 4; p++) {
            int o = (l * 4 + p) * 2;
            lc[o + 0] = rx + lc[o + 0] / nv;
            lc[o + 1] = ry + lc[o + 1] / nv;
        }
    }
}

// ---------------- multi-scale deformable attention core (2-phase) ----------------
// block = one query. Phase 1: 128 threads compute 8 heads x 16 points of tap data
// (combined weight a*w*valid, clamped byte address) into LDS. Phase 2: 8 groups of
// 32 lanes (lane=channel) do pure gather-fma.
__global__ __launch_bounds__(256) void deform(const float* __restrict__ value,
                                              const float* __restrict__ loc,
                                              const float* __restrict__ attn,
                                              __hip_bfloat16* __restrict__ out) {
    __shared__ float wS[8][16][4];
    __shared__ int   aS[8][16][4];
    int q = blockIdx.x;
    int tid = threadIdx.x;

    if (tid < 128) {
        int h = tid >> 4, pp = tid & 15;
        int l = pp >> 2;
        const int starts[4] = {0, 6400, 8000, 8400};
        int Wl = 80 >> l;                         // square levels: H==W
        float lx = loc[q * 256 + h * 32 + pp * 2 + 0];
        float ly = loc[q * 256 + h * 32 + pp * 2 + 1];
        float a  = attn[q * 128 + h * 16 + pp];
        float x = lx * (float)Wl - 0.5f;
        float y = ly * (float)Wl - 0.5f;
        float x0f = floorf(x), y0f = floorf(y);
        float fx = x - x0f, fy = y - y0f;
        int x0 = (int)x0f, y0 = (int)y0f;
        float wts[4] = {(1.f - fx) * (1.f - fy), fx * (1.f - fy),
                        (1.f - fx) * fy,         fx * fy};
        int st = starts[l];
#pragma unroll
        for (int t = 0; t < 4; t++) {
            int xi = x0 + (t & 1), yi = y0 + (t >> 1);
            bool valid = (xi >= 0) & (xi < Wl) & (yi >= 0) & (yi < Wl);
            int xc = min(max(xi, 0), Wl - 1), yc = min(max(yi, 0), Wl - 1);
            wS[h][pp][t] = valid ? wts[t] * a : 0.f;
            aS[h][pp][t] = ((st + yc * Wl + xc) * 256 + h * 32) * 4;  // byte offset
        }
    }
    __syncthreads();

    int lane = tid & 31;
    const char* vb = (const char*)value;
    int h = tid >> 5;
    int lo = lane * 4;
    float acc = 0.f;
#pragma unroll
    for (int p = 0; p < 16; p++) {
        floatx4 w = *(const floatx4*)&wS[h][p][0];
        int4 av = *(const int4*)&aS[h][p][0];
        acc += w[0] * *(const float*)(vb + av.x + lo);
        acc += w[1] * *(const float*)(vb + av.y + lo);
        acc += w[2] * *(const float*)(vb + av.z + lo);
        acc += w[3] * *(const float*)(vb + av.w + lo);
    }
    out[q * 256 + tid] = __float2bfloat16(acc);
}

// ---------------- layernorm(a+b)*g+be; optional bf16 second output ----------------
__global__ void layernorm(const float* __restrict__ a, const float* __restrict__ b,
                          const float* __restrict__ g, const float* __restrict__ be,
                          float* __restrict__ outf, __hip_bfloat16* __restrict__ outb) {
    int q = blockIdx.x;
    int c = threadIdx.x;
    float v = a[q * 256 + c] + b[q * 256 + c];

    __shared__ float red[4];
    float s = v;
#pragma unroll
    for (int o = 32; o > 0; o >>= 1) s += __shfl_down(s, o, 64);
    if ((c & 63) == 0) red[c >> 6] = s;
    __syncthreads();
    float m = (red[0] + red[1] + red[2] + red[3]) * (1.f / 256.f);
    __syncthreads();

    float d = v - m;
    s = d * d;
#pragma unroll
    for (int o = 32; o > 0; o >>= 1) s += __shfl_down(s, o, 64);
    if ((c & 63) == 0) red[c >> 6] = s;
    __syncthreads();
    float var = (red[0] + red[1] + red[2] + red[3]) * (1.f / 256.f);
    float r = rsqrtf(var + 1e-5f);
    float o = d * r * g[c] + be[c];
    outf[q * 256 + c] = o;
    if (outb) outb[q * 256 + c] = __float2bfloat16(o);
}

extern "C" void kernel_launch(void* const* d_in, const int* in_sizes, int n_in,
                              void* d_out, int out_size, void* d_ws, size_t ws_size,
                              hipStream_t stream) {
    const float* src  = (const float*)d_in[0];
    const float* pos  = (const float*)d_in[1];
    const float* refp = (const float*)d_in[2];
    const float* Wo   = (const float*)d_in[6];
    const float* bo   = (const float*)d_in[7];
    const float* Wa   = (const float*)d_in[8];
    const float* ba   = (const float*)d_in[9];
    const float* Wv   = (const float*)d_in[10];
    const float* bv   = (const float*)d_in[11];
    const float* Wout = (const float*)d_in[12];
    const float* bout = (const float*)d_in[13];
    const float* W1   = (const float*)d_in[14];
    const float* b1   = (const float*)d_in[15];
    const float* W2   = (const float*)d_in[16];
    const float* b2   = (const float*)d_in[17];
    const float* g1   = (const float*)d_in[18];
    const float* be1  = (const float*)d_in[19];
    const float* g2   = (const float*)d_in[20];
    const float* be2  = (const float*)d_in[21];
    float* out = (float*)d_out;
    char* ws = (char*)d_ws;

    // ---- workspace layout (bytes), liveness-reused ----
    __hip_bfloat16* WoT   = (__hip_bfloat16*)(ws + 0);
    __hip_bfloat16* WaT   = (__hip_bfloat16*)(ws + 131072);
    __hip_bfloat16* WvT   = (__hip_bfloat16*)(ws + 196608);
    __hip_bfloat16* WoutT = (__hip_bfloat16*)(ws + 327680);
    __hip_bfloat16* W1T   = (__hip_bfloat16*)(ws + 458752);
    __hip_bfloat16* W2T   = (__hip_bfloat16*)(ws + 983040);
    __hip_bfloat16* qb    = (__hip_bfloat16*)(ws + 1507328);   // 8500x256 bf16
    __hip_bfloat16* srcb  = (__hip_bfloat16*)(ws + 5859328);   // 8500x256 bf16
    float*          locb  = (float*)(ws + 10211328);           // 8500x256 f32
    float*          attnb = (float*)(ws + 18915328);           // 8500x128 f32
    float*          valb  = (float*)(ws + 23267328);           // 8500x256 f32
    __hip_bfloat16* hb    = (__hip_bfloat16*)(ws + 31971328);  // 8500x1024 bf16
    // reuse (liveness-disjoint):
    __hip_bfloat16* aob  = qb;
    float*          src2 = valb;
    float*          x1   = locb;
    __hip_bfloat16* x1b  = srcb;
    float*          ffnb = valb;

    int n = LTOT * D;
    prep<<<(n + 255) / 256, 256, 0, stream>>>(src, pos, qb, srcb, n);
    transpose_all<<<dim3(32, 32, 6), 256, 0, stream>>>(Wo, Wa, Wv, Wout, W1, W2,
                                                       WoT, WaT, WvT, WoutT, W1T, W2T);

    gemm_mfma<64, 64><<<dim3(4, 133), 256, 0, stream>>>(qb, WoT, bo, locb, nullptr, LTOT, 256, 256, 0);
    gemm_mfma<64, 64><<<dim3(2, 133), 256, 0, stream>>>(qb, WaT, ba, attnb, nullptr, LTOT, 128, 256, 0);
    gemm_mfma<64, 64><<<dim3(4, 133), 256, 0, stream>>>(srcb, WvT, bv, valb, nullptr, LTOT, 256, 256, 0);

    softmax_loc<<<(LTOT * NH + 255) / 256, 256, 0, stream>>>(refp, attnb, locb);
    deform<<<LTOT, 256, 0, stream>>>(valb, locb, attnb, aob);

    gemm_mfma<64, 64><<<dim3(4, 133), 256, 0, stream>>>(aob, WoutT, bout, src2, nullptr, LTOT, 256, 256, 0);
    layernorm<<<LTOT, 256, 0, stream>>>(src, src2, g1, be1, x1, x1b);
    gemm_mfma<128, 128><<<dim3(8, 67), 256, 0, stream>>>(x1b, W1T, b1, nullptr, hb, LTOT, 1024, 256, 1);
    gemm_mfma<64, 64><<<dim3(4, 133), 256, 0, stream>>>(hb, W2T, b2, ffnb, nullptr, LTOT, 256, 1024, 0);
    layernorm<<<LTOT, 256, 0, stream>>>(x1, ffnb, g2, be2, out, nullptr);
}

// Round 4
// 224.800 us; speedup vs baseline: 4.1969x; 1.2898x over previous
//
#include <hip/hip_runtime.h>
#include <hip/hip_bf16.h>

#define D 256
#define NH 8
#define DH 32
#define NL 4
#define NP 4
#define DFF 1024
#define LTOT 8500

typedef __bf16 bf16x8 __attribute__((ext_vector_type(8)));
typedef float floatx4 __attribute__((ext_vector_type(4)));

// ---------------- prep: qb = bf16(src+pos), srcb = bf16(src) ----------------
__global__ void prep(const float* __restrict__ src, const float* __restrict__ pos,
                     __hip_bfloat16* __restrict__ qb, __hip_bfloat16* __restrict__ srcb, int n) {
    int i = blockIdx.x * blockDim.x + threadIdx.x;
    if (i < n) {
        float s = src[i];
        srcb[i] = __float2bfloat16(s);
        qb[i] = __float2bfloat16(s + pos[i]);
    }
}

// ---------------- transpose+convert all 6 weights: W[K][N] fp32 -> WT[N][K] bf16 ----------------
__global__ void transpose_all(const float* W0, const float* W1_, const float* W2_,
                              const float* W3, const float* W4, const float* W5,
                              __hip_bfloat16* T0, __hip_bfloat16* T1, __hip_bfloat16* T2,
                              __hip_bfloat16* T3, __hip_bfloat16* T4, __hip_bfloat16* T5) {
    const float* W; __hip_bfloat16* T; int K, N;
    switch (blockIdx.z) {
        case 0: W = W0; T = T0; K = 256;  N = 256;  break; // Wo
        case 1: W = W1_; T = T1; K = 256; N = 128;  break; // Wa
        case 2: W = W2_; T = T2; K = 256; N = 256;  break; // Wv
        case 3: W = W3; T = T3; K = 256;  N = 256;  break; // Wout
        case 4: W = W4; T = T4; K = 256;  N = 1024; break; // W1
        default: W = W5; T = T5; K = 1024; N = 256; break; // W2
    }
    int bx = blockIdx.x, by = blockIdx.y;
    if (bx >= (N >> 5) || by >= (K >> 5)) return;
    __shared__ float t[32][33];
    int n0 = bx * 32, k0 = by * 32;
    int tx = threadIdx.x & 31, ty = threadIdx.x >> 5;
#pragma unroll
    for (int i = 0; i < 32; i += 8)
        t[ty + i][tx] = W[(size_t)(k0 + ty + i) * N + n0 + tx];
    __syncthreads();
#pragma unroll
    for (int i = 0; i < 32; i += 8)
        T[(size_t)(n0 + ty + i) * K + k0 + tx] = __float2bfloat16(t[tx][ty + i]);
}

// ---------------- generic bf16 MFMA GEMM (used for W1/relu) ----------------
template<int BM, int BN>
__global__ __launch_bounds__(256) void gemm_mfma(
    const __hip_bfloat16* __restrict__ A, const __hip_bfloat16* __restrict__ BT,
    const float* __restrict__ bias, float* __restrict__ Cf, __hip_bfloat16* __restrict__ Cb,
    int M, int N, int K, int relu) {
    constexpr int BK = 32;
    constexpr int LDA = BK + 8;
    __shared__ __hip_bfloat16 sA[BM * LDA];
    __shared__ __hip_bfloat16 sB[BN * LDA];

    int tid = threadIdx.x;
    int wave = tid >> 6, lane = tid & 63;
    int m0 = blockIdx.y * BM;
    int n0 = blockIdx.x * BN;
    constexpr int WM = BM / 2, WN = BN / 2;
    int wm = (wave >> 1) * WM;
    int wn = (wave & 1) * WN;
    constexpr int TM = WM / 16, TN = WN / 16;

    floatx4 acc[TM][TN];
#pragma unroll
    for (int i = 0; i < TM; i++)
#pragma unroll
        for (int j = 0; j < TN; j++)
#pragma unroll
            for (int e = 0; e < 4; e++) acc[i][j][e] = 0.f;

    constexpr int RA = BM / 64, RB = BN / 64;
    int rowT = tid >> 2;
    int c16 = tid & 3;
    int lrow = lane & 15;
    int lk = (lane >> 4) * 8;

    for (int k0 = 0; k0 < K; k0 += BK) {
#pragma unroll
        for (int r = 0; r < RA; r++) {
            int row = r * 64 + rowT;
            int grow = m0 + row; if (grow >= M) grow = M - 1;
            bf16x8 v = *(const bf16x8*)(A + (size_t)grow * K + k0 + c16 * 8);
            *(bf16x8*)(&sA[row * LDA + c16 * 8]) = v;
        }
#pragma unroll
        for (int r = 0; r < RB; r++) {
            int row = r * 64 + rowT;
            bf16x8 v = *(const bf16x8*)(BT + (size_t)(n0 + row) * K + k0 + c16 * 8);
            *(bf16x8*)(&sB[row * LDA + c16 * 8]) = v;
        }
        __syncthreads();

        bf16x8 af[TM], bfr[TN];
#pragma unroll
        for (int tm = 0; tm < TM; tm++)
            af[tm] = *(const bf16x8*)(&sA[(wm + tm * 16 + lrow) * LDA + lk]);
#pragma unroll
        for (int tn = 0; tn < TN; tn++)
            bfr[tn] = *(const bf16x8*)(&sB[(wn + tn * 16 + lrow) * LDA + lk]);
#pragma unroll
        for (int tm = 0; tm < TM; tm++)
#pragma unroll
            for (int tn = 0; tn < TN; tn++)
                acc[tm][tn] = __builtin_amdgcn_mfma_f32_16x16x32_bf16(af[tm], bfr[tn], acc[tm][tn], 0, 0, 0);
        __syncthreads();
    }

    int lcol = lane & 15;
    int lr4 = (lane >> 4) * 4;
#pragma unroll
    for (int tm = 0; tm < TM; tm++) {
#pragma unroll
        for (int i = 0; i < 4; i++) {
            int row = m0 + wm + tm * 16 + lr4 + i;
            if (row < M) {
#pragma unroll
                for (int tn = 0; tn < TN; tn++) {
                    int col = n0 + wn + tn * 16 + lcol;
                    float v = acc[tm][tn][i] + bias[col];
                    if (relu) v = fmaxf(v, 0.f);
                    if (Cf) Cf[(size_t)row * N + col] = v;
                    if (Cb) Cb[(size_t)row * N + col] = __float2bfloat16(v);
                }
            }
        }
    }
}

// ---------------- fused projection GEMM: [Wo | Wa | Wv], N=640 ----------------
// cols 0-255: qb@Wo -> locb f32 (stride 256); 256-383: qb@Wa -> attnb f32 (stride 128);
// 384-639: srcb@Wv -> valb bf16 (stride 256).
__global__ __launch_bounds__(256) void proj_fused(
    const __hip_bfloat16* __restrict__ qb, const __hip_bfloat16* __restrict__ srcb,
    const __hip_bfloat16* __restrict__ WoT, const __hip_bfloat16* __restrict__ WaT,
    const __hip_bfloat16* __restrict__ WvT,
    const float* __restrict__ bo, const float* __restrict__ ba, const float* __restrict__ bv,
    float* __restrict__ locb, float* __restrict__ attnb, __hip_bfloat16* __restrict__ valb,
    int M) {
    constexpr int BM = 64, BN = 64, BK = 32, K = 256;
    constexpr int LDA = BK + 8;
    __shared__ __hip_bfloat16 sA[BM * LDA];
    __shared__ __hip_bfloat16 sB[BN * LDA];

    int n0 = blockIdx.x * BN;
    int m0 = blockIdx.y * BM;

    const __hip_bfloat16* A;
    const __hip_bfloat16* BT;
    const float* bias;
    int ncol0, Nout;
    float* Cf; __hip_bfloat16* Cb;
    if (n0 < 256)      { A = qb;   BT = WoT; bias = bo; ncol0 = n0;       Nout = 256; Cf = locb;  Cb = nullptr; }
    else if (n0 < 384) { A = qb;   BT = WaT; bias = ba; ncol0 = n0 - 256; Nout = 128; Cf = attnb; Cb = nullptr; }
    else               { A = srcb; BT = WvT; bias = bv; ncol0 = n0 - 384; Nout = 256; Cf = nullptr; Cb = valb; }

    int tid = threadIdx.x;
    int wave = tid >> 6, lane = tid & 63;
    int wm = (wave >> 1) * 32;
    int wn = (wave & 1) * 32;

    floatx4 acc[2][2];
#pragma unroll
    for (int i = 0; i < 2; i++)
#pragma unroll
        for (int j = 0; j < 2; j++)
#pragma unroll
            for (int e = 0; e < 4; e++) acc[i][j][e] = 0.f;

    int rowT = tid >> 2, c16 = tid & 3;
    int lrow = lane & 15, lk = (lane >> 4) * 8;

    for (int k0 = 0; k0 < K; k0 += BK) {
        {
            int grow = m0 + rowT; if (grow >= M) grow = M - 1;
            *(bf16x8*)(&sA[rowT * LDA + c16 * 8]) =
                *(const bf16x8*)(A + (size_t)grow * K + k0 + c16 * 8);
            *(bf16x8*)(&sB[rowT * LDA + c16 * 8]) =
                *(const bf16x8*)(BT + (size_t)(ncol0 + rowT) * K + k0 + c16 * 8);
        }
        __syncthreads();
        bf16x8 af[2], bfr[2];
#pragma unroll
        for (int t = 0; t < 2; t++) {
            af[t]  = *(const bf16x8*)(&sA[(wm + t * 16 + lrow) * LDA + lk]);
            bfr[t] = *(const bf16x8*)(&sB[(wn + t * 16 + lrow) * LDA + lk]);
        }
#pragma unroll
        for (int tm = 0; tm < 2; tm++)
#pragma unroll
            for (int tn = 0; tn < 2; tn++)
                acc[tm][tn] = __builtin_amdgcn_mfma_f32_16x16x32_bf16(af[tm], bfr[tn], acc[tm][tn], 0, 0, 0);
        __syncthreads();
    }

    int lcol = lane & 15, lr4 = (lane >> 4) * 4;
#pragma unroll
    for (int tm = 0; tm < 2; tm++) {
#pragma unroll
        for (int i = 0; i < 4; i++) {
            int row = m0 + wm + tm * 16 + lr4 + i;
            if (row < M) {
#pragma unroll
                for (int tn = 0; tn < 2; tn++) {
                    int col = ncol0 + wn + tn * 16 + lcol;
                    float v = acc[tm][tn][i] + bias[col];
                    if (Cf) Cf[(size_t)row * Nout + col] = v;
                    else    Cb[(size_t)row * Nout + col] = __float2bfloat16(v);
                }
            }
        }
    }
}

// ---------------- softmax over 16 logits + sampling-location computation ----------------
__global__ void softmax_loc(const float* __restrict__ refp, float* __restrict__ attn,
                            float* __restrict__ loc) {
    int g = blockIdx.x * blockDim.x + threadIdx.x;
    if (g >= LTOT * NH) return;
    int q = g >> 3, h = g & 7;

    float* lg = attn + q * (NH * NL * NP) + h * (NL * NP);
    float v[16];
    float mx = -1e30f;
#pragma unroll
    for (int j = 0; j < 16; j++) { v[j] = lg[j]; mx = fmaxf(mx, v[j]); }
    float s = 0.f;
#pragma unroll
    for (int j = 0; j < 16; j++) { v[j] = __expf(v[j] - mx); s += v[j]; }
    float inv = 1.f / s;
#pragma unroll
    for (int j = 0; j < 16; j++) lg[j] = v[j] * inv;

    float* lc = loc + q * 256 + h * 32;
#pragma unroll
    for (int l = 0; l < 4; l++) {
        float nv = (float)(80 >> l);
        float rx = refp[(q * 4 + l) * 2 + 0];
        float ry = refp[(q * 4 + l) * 2 + 1];
#pragma unroll
        for (int p = 0; p < 4; p++) {
            int o = (l * 4 + p) * 2;
            lc[o + 0] = rx + lc[o + 0] / nv;
            lc[o + 1] = ry + lc[o + 1] / nv;
        }
    }
}

// ---------------- deform core: bf16 value, 2 queries per 256-thr block ----------------
// Phase 1: 256 threads compute 2q x 8h x 16pt tap data (weight, byte addr) into LDS.
// Phase 2: 16 lanes per (q,h); each lane = 2 channels via ushort2 loads.
__global__ __launch_bounds__(256) void deform(const __hip_bfloat16* __restrict__ value,
                                              const float* __restrict__ loc,
                                              const float* __restrict__ attn,
                                              __hip_bfloat16* __restrict__ out) {
    __shared__ float wS[2][8][16][4];
    __shared__ int   aS[2][8][16][4];
    int tid = threadIdx.x;
    int q0 = blockIdx.x * 2;

    {   // phase 1: one thread per (sub, h, pp)
        int sub = tid >> 7, h = (tid >> 4) & 7, pp = tid & 15;
        int q = q0 + sub;
        int l = pp >> 2;
        const int starts[4] = {0, 6400, 8000, 8400};
        int Wl = 80 >> l;
        float lx = loc[q * 256 + h * 32 + pp * 2 + 0];
        float ly = loc[q * 256 + h * 32 + pp * 2 + 1];
        float a  = attn[q * 128 + h * 16 + pp];
        float x = lx * (float)Wl - 0.5f;
        float y = ly * (float)Wl - 0.5f;
        float x0f = floorf(x), y0f = floorf(y);
        float fx = x - x0f, fy = y - y0f;
        int x0 = (int)x0f, y0 = (int)y0f;
        float wts[4] = {(1.f - fx) * (1.f - fy), fx * (1.f - fy),
                        (1.f - fx) * fy,         fx * fy};
        int st = starts[l];
#pragma unroll
        for (int t = 0; t < 4; t++) {
            int xi = x0 + (t & 1), yi = y0 + (t >> 1);
            bool valid = (xi >= 0) & (xi < Wl) & (yi >= 0) & (yi < Wl);
            int xc = min(max(xi, 0), Wl - 1), yc = min(max(yi, 0), Wl - 1);
            wS[sub][h][pp][t] = valid ? wts[t] * a : 0.f;
            aS[sub][h][pp][t] = (st + yc * Wl + xc) * 512 + h * 64;  // byte offset (bf16 row)
        }
    }
    __syncthreads();

    // phase 2
    int sub = tid >> 7, h = (tid >> 4) & 7, l16 = tid & 15;
    int q = q0 + sub;
    const char* vb = (const char*)value;
    int lo = l16 * 4;
    float acc0 = 0.f, acc1 = 0.f;
#pragma unroll
    for (int p = 0; p < 16; p++) {
        floatx4 w = *(const floatx4*)&wS[sub][h][p][0];
        int4 av = *(const int4*)&aS[sub][h][p][0];
        unsigned u0 = *(const unsigned*)(vb + av.x + lo);
        unsigned u1 = *(const unsigned*)(vb + av.y + lo);
        unsigned u2 = *(const unsigned*)(vb + av.z + lo);
        unsigned u3 = *(const unsigned*)(vb + av.w + lo);
        acc0 += w[0] * __uint_as_float(u0 << 16);
        acc1 += w[0] * __uint_as_float(u0 & 0xffff0000u);
        acc0 += w[1] * __uint_as_float(u1 << 16);
        acc1 += w[1] * __uint_as_float(u1 & 0xffff0000u);
        acc0 += w[2] * __uint_as_float(u2 << 16);
        acc1 += w[2] * __uint_as_float(u2 & 0xffff0000u);
        acc0 += w[3] * __uint_as_float(u3 << 16);
        acc1 += w[3] * __uint_as_float(u3 & 0xffff0000u);
    }
    __hip_bfloat162 o;
    o.x = __float2bfloat16(acc0);
    o.y = __float2bfloat16(acc1);
    *(__hip_bfloat162*)(out + q * 256 + h * 32 + l16 * 2) = o;
}

// ---------------- GEMM (N=256) + bias + residual + LayerNorm fused ----------------
// BM=32, BN=256 (full row per block). 4 waves side-by-side in N (64 cols each).
__global__ __launch_bounds__(256) void gemm_ln(
    const __hip_bfloat16* __restrict__ A, const __hip_bfloat16* __restrict__ BT,
    const float* __restrict__ bias, const float* __restrict__ resid,
    const float* __restrict__ g, const float* __restrict__ be,
    float* __restrict__ outf, __hip_bfloat16* __restrict__ outb,
    int M, int K) {
    constexpr int BM = 32, BK = 32, LDA = BK + 8;
    __shared__ __hip_bfloat16 sA[BM * LDA];
    __shared__ __hip_bfloat16 sB[256 * LDA];
    __shared__ float psum[4][32], psq[4][32], mS[32], rS[32];

    int tid = threadIdx.x;
    int wave = tid >> 6, lane = tid & 63;
    int m0 = blockIdx.x * BM;

    floatx4 acc[2][4];
#pragma unroll
    for (int i = 0; i < 2; i++)
#pragma unroll
        for (int j = 0; j < 4; j++)
#pragma unroll
            for (int e = 0; e < 4; e++) acc[i][j][e] = 0.f;

    int rowT = tid >> 2, c16 = tid & 3;
    int lrow = lane & 15, lk = (lane >> 4) * 8;

    for (int k0 = 0; k0 < K; k0 += BK) {
        if (tid < 128) {
            int grow = m0 + rowT; if (grow >= M) grow = M - 1;
            *(bf16x8*)(&sA[rowT * LDA + c16 * 8]) =
                *(const bf16x8*)(A + (size_t)grow * K + k0 + c16 * 8);
        }
#pragma unroll
        for (int r = 0; r < 4; r++) {
            int row = r * 64 + rowT;
            *(bf16x8*)(&sB[row * LDA + c16 * 8]) =
                *(const bf16x8*)(BT + (size_t)row * K + k0 + c16 * 8);
        }
        __syncthreads();
        bf16x8 af[2], bfr[4];
#pragma unroll
        for (int tm = 0; tm < 2; tm++)
            af[tm] = *(const bf16x8*)(&sA[(tm * 16 + lrow) * LDA + lk]);
#pragma unroll
        for (int tn = 0; tn < 4; tn++)
            bfr[tn] = *(const bf16x8*)(&sB[(wave * 64 + tn * 16 + lrow) * LDA + lk]);
#pragma unroll
        for (int tm = 0; tm < 2; tm++)
#pragma unroll
            for (int tn = 0; tn < 4; tn++)
                acc[tm][tn] = __builtin_amdgcn_mfma_f32_16x16x32_bf16(af[tm], bfr[tn], acc[tm][tn], 0, 0, 0);
        __syncthreads();
    }

    int lcol = lane & 15, quad = lane >> 4;
    float v[2][4][4];
#pragma unroll
    for (int tm = 0; tm < 2; tm++) {
#pragma unroll
        for (int i = 0; i < 4; i++) {
            int row = tm * 16 + quad * 4 + i;
            int grow = m0 + row; if (grow >= M) grow = M - 1;
#pragma unroll
            for (int tn = 0; tn < 4; tn++) {
                int col = wave * 64 + tn * 16 + lcol;
                v[tm][tn][i] = acc[tm][tn][i] + bias[col] + resid[(size_t)grow * 256 + col];
            }
        }
    }

    // per-row sum / sumsq over this wave's 64 cols
#pragma unroll
    for (int tm = 0; tm < 2; tm++) {
#pragma unroll
        for (int i = 0; i < 4; i++) {
            float s = 0.f, s2 = 0.f;
#pragma unroll
            for (int tn = 0; tn < 4; tn++) { float x = v[tm][tn][i]; s += x; s2 += x * x; }
#pragma unroll
            for (int m = 1; m < 16; m <<= 1) {
                s  += __shfl_xor(s, m, 64);
                s2 += __shfl_xor(s2, m, 64);
            }
            if (lcol == 0) {
                int row = tm * 16 + quad * 4 + i;
                psum[wave][row] = s;
                psq[wave][row]  = s2;
            }
        }
    }
    __syncthreads();
    if (tid < 32) {
        float s  = psum[0][tid] + psum[1][tid] + psum[2][tid] + psum[3][tid];
        float s2 = psq[0][tid]  + psq[1][tid]  + psq[2][tid]  + psq[3][tid];
        float m = s * (1.f / 256.f);
        float var = fmaxf(s2 * (1.f / 256.f) - m * m, 0.f);
        mS[tid] = m;
        rS[tid] = rsqrtf(var + 1e-5f);
    }
    __syncthreads();

#pragma unroll
    for (int tm = 0; tm < 2; tm++) {
#pragma unroll
        for (int i = 0; i < 4; i++) {
            int row = tm * 16 + quad * 4 + i;
            int grow = m0 + row;
            if (grow < M) {
                float m = mS[row], r = rS[row];
#pragma unroll
                for (int tn = 0; tn < 4; tn++) {
                    int col = wave * 64 + tn * 16 + lcol;
                    float o = (v[tm][tn][i] - m) * r * g[col] + be[col];
                    outf[(size_t)grow * 256 + col] = o;
                    if (outb) outb[(size_t)grow * 256 + col] = __float2bfloat16(o);
                }
            }
        }
    }
}

extern "C" void kernel_launch(void* const* d_in, const int* in_sizes, int n_in,
                              void* d_out, int out_size, void* d_ws, size_t ws_size,
                              hipStream_t stream) {
    const float* src  = (const float*)d_in[0];
    const float* pos  = (const float*)d_in[1];
    const float* refp = (const float*)d_in[2];
    const float* Wo   = (const float*)d_in[6];
    const float* bo   = (const float*)d_in[7];
    const float* Wa   = (const float*)d_in[8];
    const float* ba   = (const float*)d_in[9];
    const float* Wv   = (const float*)d_in[10];
    const float* bv   = (const float*)d_in[11];
    const float* Wout = (const float*)d_in[12];
    const float* bout = (const float*)d_in[13];
    const float* W1   = (const float*)d_in[14];
    const float* b1   = (const float*)d_in[15];
    const float* W2   = (const float*)d_in[16];
    const float* b2   = (const float*)d_in[17];
    const float* g1   = (const float*)d_in[18];
    const float* be1  = (const float*)d_in[19];
    const float* g2   = (const float*)d_in[20];
    const float* be2  = (const float*)d_in[21];
    float* out = (float*)d_out;
    char* ws = (char*)d_ws;

    // ---- workspace layout (bytes), liveness-reused ----
    __hip_bfloat16* WoT   = (__hip_bfloat16*)(ws + 0);
    __hip_bfloat16* WaT   = (__hip_bfloat16*)(ws + 131072);
    __hip_bfloat16* WvT   = (__hip_bfloat16*)(ws + 196608);
    __hip_bfloat16* WoutT = (__hip_bfloat16*)(ws + 327680);
    __hip_bfloat16* W1T   = (__hip_bfloat16*)(ws + 458752);
    __hip_bfloat16* W2T   = (__hip_bfloat16*)(ws + 983040);
    __hip_bfloat16* qb    = (__hip_bfloat16*)(ws + 1507328);   // 8500x256 bf16
    __hip_bfloat16* srcb  = (__hip_bfloat16*)(ws + 5859328);   // 8500x256 bf16
    float*          locb  = (float*)(ws + 10211328);           // 8500x256 f32
    float*          attnb = (float*)(ws + 18915328);           // 8500x128 f32
    __hip_bfloat16* valb  = (__hip_bfloat16*)(ws + 23267328);  // 8500x256 bf16
    __hip_bfloat16* hb    = (__hip_bfloat16*)(ws + 31971328);  // 8500x1024 bf16
    // reuse (liveness-disjoint):
    __hip_bfloat16* aob  = qb;      // qb dead after proj_fused
    float*          x1   = locb;    // locb dead after deform
    __hip_bfloat16* x1b  = srcb;    // srcb dead after proj_fused

    int n = LTOT * D;
    prep<<<(n + 255) / 256, 256, 0, stream>>>(src, pos, qb, srcb, n);
    transpose_all<<<dim3(32, 32, 6), 256, 0, stream>>>(Wo, Wa, Wv, Wout, W1, W2,
                                                       WoT, WaT, WvT, WoutT, W1T, W2T);

    proj_fused<<<dim3(10, 133), 256, 0, stream>>>(qb, srcb, WoT, WaT, WvT, bo, ba, bv,
                                                  locb, attnb, valb, LTOT);

    softmax_loc<<<(LTOT * NH + 255) / 256, 256, 0, stream>>>(refp, attnb, locb);
    deform<<<4250, 256, 0, stream>>>(valb, locb, attnb, aob);

    gemm_ln<<<266, 256, 0, stream>>>(aob, WoutT, bout, src, g1, be1, x1, x1b, LTOT, 256);
    gemm_mfma<128, 128><<<dim3(8, 67), 256, 0, stream>>>(x1b, W1T, b1, nullptr, hb, LTOT, 1024, 256, 1);
    gemm_ln<<<266, 256, 0, stream>>>(hb, W2T, b2, x1, g2, be2, out, nullptr, LTOT, 1024);
}

// Round 5
// 219.746 us; speedup vs baseline: 4.2934x; 1.0230x over previous
//
#include <hip/hip_runtime.h>
#include <hip/hip_bf16.h>
#include <string.h>

#define D 256
#define NH 8
#define DH 32
#define NL 4
#define NP 4
#define DFF 1024
#define LTOT 8500

typedef __bf16 bf16x8 __attribute__((ext_vector_type(8)));
typedef float floatx4 __attribute__((ext_vector_type(4)));

__device__ inline unsigned bpack(float a, float b) {
    __hip_bfloat16 ha = __float2bfloat16(a), hb = __float2bfloat16(b);
    unsigned short ua, ub;
    memcpy(&ua, &ha, 2); memcpy(&ub, &hb, 2);
    return (unsigned)ua | ((unsigned)ub << 16);
}

// ---------------- prep: qb = bf16(src+pos), srcb = bf16(src); 4 elems/thread ----------------
__global__ void prep(const float* __restrict__ src, const float* __restrict__ pos,
                     unsigned* __restrict__ qb, unsigned* __restrict__ srcb, int n4) {
    int i = blockIdx.x * blockDim.x + threadIdx.x;
    if (i >= n4) return;
    float4 s = *(const float4*)(src + i * 4);
    float4 p = *(const float4*)(pos + i * 4);
    uint2 sb, qb2;
    sb.x = bpack(s.x, s.y); sb.y = bpack(s.z, s.w);
    qb2.x = bpack(s.x + p.x, s.y + p.y); qb2.y = bpack(s.z + p.z, s.w + p.w);
    *(uint2*)(srcb + i * 2) = sb;
    *(uint2*)(qb + i * 2) = qb2;
}

// ---------------- transpose+convert 6 weights, exact 736-tile grid ----------------
__global__ void transpose_all(const float* W0, const float* W1_, const float* W2_,
                              const float* W3, const float* W4, const float* W5,
                              __hip_bfloat16* T0, __hip_bfloat16* T1, __hip_bfloat16* T2,
                              __hip_bfloat16* T3, __hip_bfloat16* T4, __hip_bfloat16* T5) {
    const int cum[7] = {0, 64, 96, 160, 224, 480, 736};
    int id = blockIdx.x;
    int mi = 0;
    while (id >= cum[mi + 1]) mi++;
    int lid = id - cum[mi];
    const float* W; __hip_bfloat16* T; int K, N;
    switch (mi) {
        case 0: W = W0; T = T0; K = 256;  N = 256;  break;
        case 1: W = W1_; T = T1; K = 256; N = 128;  break;
        case 2: W = W2_; T = T2; K = 256; N = 256;  break;
        case 3: W = W3; T = T3; K = 256;  N = 256;  break;
        case 4: W = W4; T = T4; K = 256;  N = 1024; break;
        default: W = W5; T = T5; K = 1024; N = 256; break;
    }
    int ntx = N >> 5;
    int n0 = (lid % ntx) * 32, k0 = (lid / ntx) * 32;
    __shared__ float t[32][33];
    int tx = threadIdx.x & 31, ty = threadIdx.x >> 5;
#pragma unroll
    for (int i = 0; i < 32; i += 8)
        t[ty + i][tx] = W[(size_t)(k0 + ty + i) * N + n0 + tx];
    __syncthreads();
#pragma unroll
    for (int i = 0; i < 32; i += 8)
        T[(size_t)(n0 + ty + i) * K + k0 + tx] = __float2bfloat16(t[tx][ty + i]);
}

// ---------------- generic bf16 MFMA GEMM (used for W1/relu) ----------------
template<int BM, int BN>
__global__ __launch_bounds__(256) void gemm_mfma(
    const __hip_bfloat16* __restrict__ A, const __hip_bfloat16* __restrict__ BT,
    const float* __restrict__ bias, float* __restrict__ Cf, __hip_bfloat16* __restrict__ Cb,
    int M, int N, int K, int relu) {
    constexpr int BK = 32;
    constexpr int LDA = BK + 8;
    __shared__ __hip_bfloat16 sA[BM * LDA];
    __shared__ __hip_bfloat16 sB[BN * LDA];

    int tid = threadIdx.x;
    int wave = tid >> 6, lane = tid & 63;
    int m0 = blockIdx.y * BM;
    int n0 = blockIdx.x * BN;
    constexpr int WM = BM / 2, WN = BN / 2;
    int wm = (wave >> 1) * WM;
    int wn = (wave & 1) * WN;
    constexpr int TM = WM / 16, TN = WN / 16;

    floatx4 acc[TM][TN];
#pragma unroll
    for (int i = 0; i < TM; i++)
#pragma unroll
        for (int j = 0; j < TN; j++)
#pragma unroll
            for (int e = 0; e < 4; e++) acc[i][j][e] = 0.f;

    constexpr int RA = BM / 64, RB = BN / 64;
    int rowT = tid >> 2;
    int c16 = tid & 3;
    int lrow = lane & 15;
    int lk = (lane >> 4) * 8;

    for (int k0 = 0; k0 < K; k0 += BK) {
#pragma unroll
        for (int r = 0; r < RA; r++) {
            int row = r * 64 + rowT;
            int grow = m0 + row; if (grow >= M) grow = M - 1;
            bf16x8 v = *(const bf16x8*)(A + (size_t)grow * K + k0 + c16 * 8);
            *(bf16x8*)(&sA[row * LDA + c16 * 8]) = v;
        }
#pragma unroll
        for (int r = 0; r < RB; r++) {
            int row = r * 64 + rowT;
            bf16x8 v = *(const bf16x8*)(BT + (size_t)(n0 + row) * K + k0 + c16 * 8);
            *(bf16x8*)(&sB[row * LDA + c16 * 8]) = v;
        }
        __syncthreads();

        bf16x8 af[TM], bfr[TN];
#pragma unroll
        for (int tm = 0; tm < TM; tm++)
            af[tm] = *(const bf16x8*)(&sA[(wm + tm * 16 + lrow) * LDA + lk]);
#pragma unroll
        for (int tn = 0; tn < TN; tn++)
            bfr[tn] = *(const bf16x8*)(&sB[(wn + tn * 16 + lrow) * LDA + lk]);
#pragma unroll
        for (int tm = 0; tm < TM; tm++)
#pragma unroll
            for (int tn = 0; tn < TN; tn++)
                acc[tm][tn] = __builtin_amdgcn_mfma_f32_16x16x32_bf16(af[tm], bfr[tn], acc[tm][tn], 0, 0, 0);
        __syncthreads();
    }

    int lcol = lane & 15;
    int lr4 = (lane >> 4) * 4;
#pragma unroll
    for (int tm = 0; tm < TM; tm++) {
#pragma unroll
        for (int i = 0; i < 4; i++) {
            int row = m0 + wm + tm * 16 + lr4 + i;
            if (row < M) {
#pragma unroll
                for (int tn = 0; tn < TN; tn++) {
                    int col = n0 + wn + tn * 16 + lcol;
                    float v = acc[tm][tn][i] + bias[col];
                    if (relu) v = fmaxf(v, 0.f);
                    if (Cf) Cf[(size_t)row * N + col] = v;
                    if (Cb) Cb[(size_t)row * N + col] = __float2bfloat16(v);
                }
            }
        }
    }
}

// ---------------- fused projection GEMM: [Wo | Wa | Wv], N=640 ----------------
__global__ __launch_bounds__(256) void proj_fused(
    const __hip_bfloat16* __restrict__ qb, const __hip_bfloat16* __restrict__ srcb,
    const __hip_bfloat16* __restrict__ WoT, const __hip_bfloat16* __restrict__ WaT,
    const __hip_bfloat16* __restrict__ WvT,
    const float* __restrict__ bo, const float* __restrict__ ba, const float* __restrict__ bv,
    float* __restrict__ locb, float* __restrict__ attnb, __hip_bfloat16* __restrict__ valb,
    int M) {
    constexpr int BM = 64, BN = 64, BK = 32, K = 256;
    constexpr int LDA = BK + 8;
    __shared__ __hip_bfloat16 sA[BM * LDA];
    __shared__ __hip_bfloat16 sB[BN * LDA];

    int n0 = blockIdx.x * BN;
    int m0 = blockIdx.y * BM;

    const __hip_bfloat16* A;
    const __hip_bfloat16* BT;
    const float* bias;
    int ncol0, Nout;
    float* Cf; __hip_bfloat16* Cb;
    if (n0 < 256)      { A = qb;   BT = WoT; bias = bo; ncol0 = n0;       Nout = 256; Cf = locb;  Cb = nullptr; }
    else if (n0 < 384) { A = qb;   BT = WaT; bias = ba; ncol0 = n0 - 256; Nout = 128; Cf = attnb; Cb = nullptr; }
    else               { A = srcb; BT = WvT; bias = bv; ncol0 = n0 - 384; Nout = 256; Cf = nullptr; Cb = valb; }

    int tid = threadIdx.x;
    int wave = tid >> 6, lane = tid & 63;
    int wm = (wave >> 1) * 32;
    int wn = (wave & 1) * 32;

    floatx4 acc[2][2];
#pragma unroll
    for (int i = 0; i < 2; i++)
#pragma unroll
        for (int j = 0; j < 2; j++)
#pragma unroll
            for (int e = 0; e < 4; e++) acc[i][j][e] = 0.f;

    int rowT = tid >> 2, c16 = tid & 3;
    int lrow = lane & 15, lk = (lane >> 4) * 8;

    for (int k0 = 0; k0 < K; k0 += BK) {
        {
            int grow = m0 + rowT; if (grow >= M) grow = M - 1;
            *(bf16x8*)(&sA[rowT * LDA + c16 * 8]) =
                *(const bf16x8*)(A + (size_t)grow * K + k0 + c16 * 8);
            *(bf16x8*)(&sB[rowT * LDA + c16 * 8]) =
                *(const bf16x8*)(BT + (size_t)(ncol0 + rowT) * K + k0 + c16 * 8);
        }
        __syncthreads();
        bf16x8 af[2], bfr[2];
#pragma unroll
        for (int t = 0; t < 2; t++) {
            af[t]  = *(const bf16x8*)(&sA[(wm + t * 16 + lrow) * LDA + lk]);
            bfr[t] = *(const bf16x8*)(&sB[(wn + t * 16 + lrow) * LDA + lk]);
        }
#pragma unroll
        for (int tm = 0; tm < 2; tm++)
#pragma unroll
            for (int tn = 0; tn < 2; tn++)
                acc[tm][tn] = __builtin_amdgcn_mfma_f32_16x16x32_bf16(af[tm], bfr[tn], acc[tm][tn], 0, 0, 0);
        __syncthreads();
    }

    int lcol = lane & 15, lr4 = (lane >> 4) * 4;
#pragma unroll
    for (int tm = 0; tm < 2; tm++) {
#pragma unroll
        for (int i = 0; i < 4; i++) {
            int row = m0 + wm + tm * 16 + lr4 + i;
            if (row < M) {
#pragma unroll
                for (int tn = 0; tn < 2; tn++) {
                    int col = ncol0 + wn + tn * 16 + lcol;
                    float v = acc[tm][tn][i] + bias[col];
                    if (Cf) Cf[(size_t)row * Nout + col] = v;
                    else    Cb[(size_t)row * Nout + col] = __float2bfloat16(v);
                }
            }
        }
    }
}

// ---------------- deform core: softmax+loc fused, 4 queries/block, 8 lanes/(q,h) ----------------
// Phase 1: thread = (sub, h, t8); handles points t8 and t8+8; softmax over the 8-lane
// group via shfl_xor(1,2,4). Writes combined weight + byte addr for 4 taps into LDS.
// Phase 2: 8 lanes per (q,h); each lane = 4 channels via ushort4 (8 B) loads.
__global__ __launch_bounds__(256) void deform(const __hip_bfloat16* __restrict__ value,
                                              const float* __restrict__ locraw,
                                              const float* __restrict__ logits,
                                              const float* __restrict__ refp,
                                              __hip_bfloat16* __restrict__ out) {
    __shared__ float wS[4][8][16][4];
    __shared__ int   aS[4][8][16][4];
    int tid = threadIdx.x;
    int q0 = blockIdx.x * 4;

    {   // phase 1
        int sub = tid >> 6, h = (tid >> 3) & 7, t8 = tid & 7;
        int q = q0 + sub;
        const float* lg = logits + q * 128 + h * 16;
        float l0 = lg[t8], l1 = lg[t8 + 8];
        float mx = fmaxf(l0, l1);
#pragma unroll
        for (int m = 1; m < 8; m <<= 1) mx = fmaxf(mx, __shfl_xor(mx, m, 64));
        float e0 = __expf(l0 - mx), e1 = __expf(l1 - mx);
        float s = e0 + e1;
#pragma unroll
        for (int m = 1; m < 8; m <<= 1) s += __shfl_xor(s, m, 64);
        float inv = 1.f / s;

        const int starts[4] = {0, 6400, 8000, 8400};
#pragma unroll
        for (int j = 0; j < 2; j++) {
            int pp = t8 + 8 * j;
            float a = (j ? e1 : e0) * inv;
            int l = pp >> 2;
            int Wl = 80 >> l;
            float nv = (float)Wl;
            float rx = refp[q * 8 + l * 2 + 0];
            float ry = refp[q * 8 + l * 2 + 1];
            float lx = rx + locraw[q * 256 + h * 32 + pp * 2 + 0] / nv;
            float ly = ry + locraw[q * 256 + h * 32 + pp * 2 + 1] / nv;
            float x = lx * nv - 0.5f;
            float y = ly * nv - 0.5f;
            float x0f = floorf(x), y0f = floorf(y);
            float fx = x - x0f, fy = y - y0f;
            int x0 = (int)x0f, y0 = (int)y0f;
            float wts[4] = {(1.f - fx) * (1.f - fy), fx * (1.f - fy),
                            (1.f - fx) * fy,         fx * fy};
            int st = starts[l];
#pragma unroll
            for (int t = 0; t < 4; t++) {
                int xi = x0 + (t & 1), yi = y0 + (t >> 1);
                bool valid = (xi >= 0) & (xi < Wl) & (yi >= 0) & (yi < Wl);
                int xc = min(max(xi, 0), Wl - 1), yc = min(max(yi, 0), Wl - 1);
                wS[sub][h][pp][t] = valid ? wts[t] * a : 0.f;
                aS[sub][h][pp][t] = (st + yc * Wl + xc) * 512 + h * 64;  // bf16 row = 512 B
            }
        }
    }
    __syncthreads();

    // phase 2: tid = sub*64 + h*8 + l8
    int sub = tid >> 6, h = (tid >> 3) & 7, l8 = tid & 7;
    int q = q0 + sub;
    const char* vb = (const char*)value;
    int lo = l8 * 8;
    float a0 = 0.f, a1 = 0.f, a2 = 0.f, a3 = 0.f;
#pragma unroll
    for (int p = 0; p < 16; p++) {
        floatx4 w = *(const floatx4*)&wS[sub][h][p][0];
        int4 av = *(const int4*)&aS[sub][h][p][0];
#pragma unroll
        for (int t = 0; t < 4; t++) {
            int ad = (t == 0) ? av.x : (t == 1) ? av.y : (t == 2) ? av.z : av.w;
            uint2 u = *(const uint2*)(vb + ad + lo);
            float wt = w[t];
            a0 += wt * __uint_as_float(u.x << 16);
            a1 += wt * __uint_as_float(u.x & 0xffff0000u);
            a2 += wt * __uint_as_float(u.y << 16);
            a3 += wt * __uint_as_float(u.y & 0xffff0000u);
        }
    }
    uint2 o;
    o.x = bpack(a0, a1);
    o.y = bpack(a2, a3);
    *(uint2*)((char*)out + q * 512 + h * 64 + l8 * 8) = o;
}

// ---------------- GEMM (N=256) + bias + residual + LayerNorm fused ----------------
__global__ __launch_bounds__(256) void gemm_ln(
    const __hip_bfloat16* __restrict__ A, const __hip_bfloat16* __restrict__ BT,
    const float* __restrict__ bias, const float* __restrict__ resid,
    const float* __restrict__ g, const float* __restrict__ be,
    float* __restrict__ outf, __hip_bfloat16* __restrict__ outb,
    int M, int K) {
    constexpr int BM = 32, BK = 32, LDA = BK + 8;
    __shared__ __hip_bfloat16 sA[BM * LDA];
    __shared__ __hip_bfloat16 sB[256 * LDA];
    __shared__ float psum[4][32], psq[4][32], mS[32], rS[32];

    int tid = threadIdx.x;
    int wave = tid >> 6, lane = tid & 63;
    int m0 = blockIdx.x * BM;

    floatx4 acc[2][4];
#pragma unroll
    for (int i = 0; i < 2; i++)
#pragma unroll
        for (int j = 0; j < 4; j++)
#pragma unroll
            for (int e = 0; e < 4; e++) acc[i][j][e] = 0.f;

    int rowT = tid >> 2, c16 = tid & 3;
    int lrow = lane & 15, lk = (lane >> 4) * 8;

    for (int k0 = 0; k0 < K; k0 += BK) {
        if (tid < 128) {
            int grow = m0 + rowT; if (grow >= M) grow = M - 1;
            *(bf16x8*)(&sA[rowT * LDA + c16 * 8]) =
                *(const bf16x8*)(A + (size_t)grow * K + k0 + c16 * 8);
        }
#pragma unroll
        for (int r = 0; r < 4; r++) {
            int row = r * 64 + rowT;
            *(bf16x8*)(&sB[row * LDA + c16 * 8]) =
                *(const bf16x8*)(BT + (size_t)row * K + k0 + c16 * 8);
        }
        __syncthreads();
        bf16x8 af[2], bfr[4];
#pragma unroll
        for (int tm = 0; tm < 2; tm++)
            af[tm] = *(const bf16x8*)(&sA[(tm * 16 + lrow) * LDA + lk]);
#pragma unroll
        for (int tn = 0; tn < 4; tn++)
            bfr[tn] = *(const bf16x8*)(&sB[(wave * 64 + tn * 16 + lrow) * LDA + lk]);
#pragma unroll
        for (int tm = 0; tm < 2; tm++)
#pragma unroll
            for (int tn = 0; tn < 4; tn++)
                acc[tm][tn] = __builtin_amdgcn_mfma_f32_16x16x32_bf16(af[tm], bfr[tn], acc[tm][tn], 0, 0, 0);
        __syncthreads();
    }

    int lcol = lane & 15, quad = lane >> 4;
    float v[2][4][4];
#pragma unroll
    for (int tm = 0; tm < 2; tm++) {
#pragma unroll
        for (int i = 0; i < 4; i++) {
            int row = tm * 16 + quad * 4 + i;
            int grow = m0 + row; if (grow >= M) grow = M - 1;
#pragma unroll
            for (int tn = 0; tn < 4; tn++) {
                int col = wave * 64 + tn * 16 + lcol;
                v[tm][tn][i] = acc[tm][tn][i] + bias[col] + resid[(size_t)grow * 256 + col];
            }
        }
    }

#pragma unroll
    for (int tm = 0; tm < 2; tm++) {
#pragma unroll
        for (int i = 0; i < 4; i++) {
            float s = 0.f, s2 = 0.f;
#pragma unroll
            for (int tn = 0; tn < 4; tn++) { float x = v[tm][tn][i]; s += x; s2 += x * x; }
#pragma unroll
            for (int m = 1; m < 16; m <<= 1) {
                s  += __shfl_xor(s, m, 64);
                s2 += __shfl_xor(s2, m, 64);
            }
            if (lcol == 0) {
                int row = tm * 16 + quad * 4 + i;
                psum[wave][row] = s;
                psq[wave][row]  = s2;
            }
        }
    }
    __syncthreads();
    if (tid < 32) {
        float s  = psum[0][tid] + psum[1][tid] + psum[2][tid] + psum[3][tid];
        float s2 = psq[0][tid]  + psq[1][tid]  + psq[2][tid]  + psq[3][tid];
        float m = s * (1.f / 256.f);
        float var = fmaxf(s2 * (1.f / 256.f) - m * m, 0.f);
        mS[tid] = m;
        rS[tid] = rsqrtf(var + 1e-5f);
    }
    __syncthreads();

#pragma unroll
    for (int tm = 0; tm < 2; tm++) {
#pragma unroll
        for (int i = 0; i < 4; i++) {
            int row = tm * 16 + quad * 4 + i;
            int grow = m0 + row;
            if (grow < M) {
                float m = mS[row], r = rS[row];
#pragma unroll
                for (int tn = 0; tn < 4; tn++) {
                    int col = wave * 64 + tn * 16 + lcol;
                    float o = (v[tm][tn][i] - m) * r * g[col] + be[col];
                    outf[(size_t)grow * 256 + col] = o;
                    if (outb) outb[(size_t)grow * 256 + col] = __float2bfloat16(o);
                }
            }
        }
    }
}

extern "C" void kernel_launch(void* const* d_in, const int* in_sizes, int n_in,
                              void* d_out, int out_size, void* d_ws, size_t ws_size,
                              hipStream_t stream) {
    const float* src  = (const float*)d_in[0];
    const float* pos  = (const float*)d_in[1];
    const float* refp = (const float*)d_in[2];
    const float* Wo   = (const float*)d_in[6];
    const float* bo   = (const float*)d_in[7];
    const float* Wa   = (const float*)d_in[8];
    const float* ba   = (const float*)d_in[9];
    const float* Wv   = (const float*)d_in[10];
    const float* bv   = (const float*)d_in[11];
    const float* Wout = (const float*)d_in[12];
    const float* bout = (const float*)d_in[13];
    const float* W1   = (const float*)d_in[14];
    const float* b1   = (const float*)d_in[15];
    const float* W2   = (const float*)d_in[16];
    const float* b2   = (const float*)d_in[17];
    const float* g1   = (const float*)d_in[18];
    const float* be1  = (const float*)d_in[19];
    const float* g2   = (const float*)d_in[20];
    const float* be2  = (const float*)d_in[21];
    float* out = (float*)d_out;
    char* ws = (char*)d_ws;

    // ---- workspace layout (bytes), liveness-reused ----
    __hip_bfloat16* WoT   = (__hip_bfloat16*)(ws + 0);
    __hip_bfloat16* WaT   = (__hip_bfloat16*)(ws + 131072);
    __hip_bfloat16* WvT   = (__hip_bfloat16*)(ws + 196608);
    __hip_bfloat16* WoutT = (__hip_bfloat16*)(ws + 327680);
    __hip_bfloat16* W1T   = (__hip_bfloat16*)(ws + 458752);
    __hip_bfloat16* W2T   = (__hip_bfloat16*)(ws + 983040);
    __hip_bfloat16* qb    = (__hip_bfloat16*)(ws + 1507328);   // 8500x256 bf16
    __hip_bfloat16* srcb  = (__hip_bfloat16*)(ws + 5859328);   // 8500x256 bf16
    float*          locb  = (float*)(ws + 10211328);           // 8500x256 f32 (raw offsets)
    float*          attnb = (float*)(ws + 18915328);           // 8500x128 f32 (raw logits)
    __hip_bfloat16* valb  = (__hip_bfloat16*)(ws + 23267328);  // 8500x256 bf16
    __hip_bfloat16* hb    = (__hip_bfloat16*)(ws + 31971328);  // 8500x1024 bf16
    // reuse (liveness-disjoint):
    __hip_bfloat16* aob  = qb;      // qb dead after proj_fused+deform reads none of it
    float*          x1   = locb;    // locb dead after deform
    __hip_bfloat16* x1b  = srcb;    // srcb dead after proj_fused

    prep<<<2125, 256, 0, stream>>>(src, pos, (unsigned*)qb, (unsigned*)srcb, LTOT * D / 4);
    transpose_all<<<736, 256, 0, stream>>>(Wo, Wa, Wv, Wout, W1, W2,
                                           WoT, WaT, WvT, WoutT, W1T, W2T);

    proj_fused<<<dim3(10, 133), 256, 0, stream>>>(qb, srcb, WoT, WaT, WvT, bo, ba, bv,
                                                  locb, attnb, valb, LTOT);

    deform<<<2125, 256, 0, stream>>>(valb, locb, attnb, refp, aob);

    gemm_ln<<<266, 256, 0, stream>>>(aob, WoutT, bout, src, g1, be1, x1, x1b, LTOT, 256);
    gemm_mfma<128, 128><<<dim3(8, 67), 256, 0, stream>>>(x1b, W1T, b1, nullptr, hb, LTOT, 1024, 256, 1);
    gemm_ln<<<266, 256, 0, stream>>>(hb, W2T, b2, x1, g2, be2, out, nullptr, LTOT, 1024);
}

// Round 6
// 219.111 us; speedup vs baseline: 4.3059x; 1.0029x over previous
//
#include <hip/hip_runtime.h>
#include <hip/hip_bf16.h>
#include <string.h>

#define D 256
#define NH 8
#define DH 32
#define NL 4
#define NP 4
#define DFF 1024
#define LTOT 8500

typedef __bf16 bf16x8 __attribute__((ext_vector_type(8)));
typedef float floatx4 __attribute__((ext_vector_type(4)));

__device__ inline unsigned bpack(float a, float b) {
    __hip_bfloat16 ha = __float2bfloat16(a), hb = __float2bfloat16(b);
    unsigned short ua, ub;
    memcpy(&ua, &ha, 2); memcpy(&ub, &hb, 2);
    return (unsigned)ua | ((unsigned)ub << 16);
}

// ---------------- transpose+convert 6 weights, exact 736-tile grid ----------------
__global__ void transpose_all(const float* W0, const float* W1_, const float* W2_,
                              const float* W3, const float* W4, const float* W5,
                              __hip_bfloat16* T0, __hip_bfloat16* T1, __hip_bfloat16* T2,
                              __hip_bfloat16* T3, __hip_bfloat16* T4, __hip_bfloat16* T5) {
    const int cum[7] = {0, 64, 96, 160, 224, 480, 736};
    int id = blockIdx.x;
    int mi = 0;
    while (id >= cum[mi + 1]) mi++;
    int lid = id - cum[mi];
    const float* W; __hip_bfloat16* T; int K, N;
    switch (mi) {
        case 0: W = W0; T = T0; K = 256;  N = 256;  break;
        case 1: W = W1_; T = T1; K = 256; N = 128;  break;
        case 2: W = W2_; T = T2; K = 256; N = 256;  break;
        case 3: W = W3; T = T3; K = 256;  N = 256;  break;
        case 4: W = W4; T = T4; K = 256;  N = 1024; break;
        default: W = W5; T = T5; K = 1024; N = 256; break;
    }
    int ntx = N >> 5;
    int n0 = (lid % ntx) * 32, k0 = (lid / ntx) * 32;
    __shared__ float t[32][33];
    int tx = threadIdx.x & 31, ty = threadIdx.x >> 5;
#pragma unroll
    for (int i = 0; i < 32; i += 8)
        t[ty + i][tx] = W[(size_t)(k0 + ty + i) * N + n0 + tx];
    __syncthreads();
#pragma unroll
    for (int i = 0; i < 32; i += 8)
        T[(size_t)(n0 + ty + i) * K + k0 + tx] = __float2bfloat16(t[tx][ty + i]);
}

// ---------------- generic bf16 MFMA GEMM (used for W1/relu) ----------------
template<int BM, int BN>
__global__ __launch_bounds__(256) void gemm_mfma(
    const __hip_bfloat16* __restrict__ A, const __hip_bfloat16* __restrict__ BT,
    const float* __restrict__ bias, float* __restrict__ Cf, __hip_bfloat16* __restrict__ Cb,
    int M, int N, int K, int relu) {
    constexpr int BK = 32;
    constexpr int LDA = BK + 8;
    __shared__ __align__(16) __hip_bfloat16 sA[BM * LDA];
    __shared__ __align__(16) __hip_bfloat16 sB[BN * LDA];

    int tid = threadIdx.x;
    int wave = tid >> 6, lane = tid & 63;
    int m0 = blockIdx.y * BM;
    int n0 = blockIdx.x * BN;
    constexpr int WM = BM / 2, WN = BN / 2;
    int wm = (wave >> 1) * WM;
    int wn = (wave & 1) * WN;
    constexpr int TM = WM / 16, TN = WN / 16;

    floatx4 acc[TM][TN];
#pragma unroll
    for (int i = 0; i < TM; i++)
#pragma unroll
        for (int j = 0; j < TN; j++)
#pragma unroll
            for (int e = 0; e < 4; e++) acc[i][j][e] = 0.f;

    constexpr int RA = BM / 64, RB = BN / 64;
    int rowT = tid >> 2;
    int c16 = tid & 3;
    int lrow = lane & 15;
    int lk = (lane >> 4) * 8;

    for (int k0 = 0; k0 < K; k0 += BK) {
#pragma unroll
        for (int r = 0; r < RA; r++) {
            int row = r * 64 + rowT;
            int grow = m0 + row; if (grow >= M) grow = M - 1;
            bf16x8 v = *(const bf16x8*)(A + (size_t)grow * K + k0 + c16 * 8);
            *(bf16x8*)(&sA[row * LDA + c16 * 8]) = v;
        }
#pragma unroll
        for (int r = 0; r < RB; r++) {
            int row = r * 64 + rowT;
            bf16x8 v = *(const bf16x8*)(BT + (size_t)(n0 + row) * K + k0 + c16 * 8);
            *(bf16x8*)(&sB[row * LDA + c16 * 8]) = v;
        }
        __syncthreads();

        bf16x8 af[TM], bfr[TN];
#pragma unroll
        for (int tm = 0; tm < TM; tm++)
            af[tm] = *(const bf16x8*)(&sA[(wm + tm * 16 + lrow) * LDA + lk]);
#pragma unroll
        for (int tn = 0; tn < TN; tn++)
            bfr[tn] = *(const bf16x8*)(&sB[(wn + tn * 16 + lrow) * LDA + lk]);
#pragma unroll
        for (int tm = 0; tm < TM; tm++)
#pragma unroll
            for (int tn = 0; tn < TN; tn++)
                acc[tm][tn] = __builtin_amdgcn_mfma_f32_16x16x32_bf16(af[tm], bfr[tn], acc[tm][tn], 0, 0, 0);
        __syncthreads();
    }

    int lcol = lane & 15;
    int lr4 = (lane >> 4) * 4;
#pragma unroll
    for (int tm = 0; tm < TM; tm++) {
#pragma unroll
        for (int i = 0; i < 4; i++) {
            int row = m0 + wm + tm * 16 + lr4 + i;
            if (row < M) {
#pragma unroll
                for (int tn = 0; tn < TN; tn++) {
                    int col = n0 + wn + tn * 16 + lcol;
                    float v = acc[tm][tn][i] + bias[col];
                    if (relu) v = fmaxf(v, 0.f);
                    if (Cf) Cf[(size_t)row * N + col] = v;
                    if (Cb) Cb[(size_t)row * N + col] = __float2bfloat16(v);
                }
            }
        }
    }
}

// ---------------- fused projection GEMM: [Wo | Wa | Wv], N=640, fp32 A with on-the-fly cvt ----------------
// A = bf16(src+pos) for cols <384, bf16(src) for Wv cols. Conversion happens in LDS staging.
__global__ __launch_bounds__(256) void proj_fused(
    const float* __restrict__ src, const float* __restrict__ pos,
    const __hip_bfloat16* __restrict__ WoT, const __hip_bfloat16* __restrict__ WaT,
    const __hip_bfloat16* __restrict__ WvT,
    const float* __restrict__ bo, const float* __restrict__ ba, const float* __restrict__ bv,
    float* __restrict__ locb, float* __restrict__ attnb, __hip_bfloat16* __restrict__ valb,
    int M) {
    constexpr int BM = 64, BN = 64, BK = 32, K = 256;
    constexpr int LDA = BK + 8;
    __shared__ __align__(16) __hip_bfloat16 sA[BM * LDA];
    __shared__ __align__(16) __hip_bfloat16 sB[BN * LDA];

    int n0 = blockIdx.x * BN;
    int m0 = blockIdx.y * BM;

    const __hip_bfloat16* BT;
    const float* bias;
    int ncol0, Nout, usePos;
    float* Cf; __hip_bfloat16* Cb;
    if (n0 < 256)      { BT = WoT; bias = bo; ncol0 = n0;       Nout = 256; Cf = locb;  Cb = nullptr; usePos = 1; }
    else if (n0 < 384) { BT = WaT; bias = ba; ncol0 = n0 - 256; Nout = 128; Cf = attnb; Cb = nullptr; usePos = 1; }
    else               { BT = WvT; bias = bv; ncol0 = n0 - 384; Nout = 256; Cf = nullptr; Cb = valb; usePos = 0; }

    int tid = threadIdx.x;
    int wave = tid >> 6, lane = tid & 63;
    int wm = (wave >> 1) * 32;
    int wn = (wave & 1) * 32;

    floatx4 acc[2][2];
#pragma unroll
    for (int i = 0; i < 2; i++)
#pragma unroll
        for (int j = 0; j < 2; j++)
#pragma unroll
            for (int e = 0; e < 4; e++) acc[i][j][e] = 0.f;

    int rowT = tid >> 2, c16 = tid & 3;
    int lrow = lane & 15, lk = (lane >> 4) * 8;

    for (int k0 = 0; k0 < K; k0 += BK) {
        {
            int grow = m0 + rowT; if (grow >= M) grow = M - 1;
            const float* ap = src + (size_t)grow * K + k0 + c16 * 8;
            float4 s0 = *(const float4*)ap;
            float4 s1 = *(const float4*)(ap + 4);
            if (usePos) {
                const float* pp = pos + (size_t)grow * K + k0 + c16 * 8;
                float4 p0 = *(const float4*)pp;
                float4 p1 = *(const float4*)(pp + 4);
                s0.x += p0.x; s0.y += p0.y; s0.z += p0.z; s0.w += p0.w;
                s1.x += p1.x; s1.y += p1.y; s1.z += p1.z; s1.w += p1.w;
            }
            uint4 pk;
            pk.x = bpack(s0.x, s0.y); pk.y = bpack(s0.z, s0.w);
            pk.z = bpack(s1.x, s1.y); pk.w = bpack(s1.z, s1.w);
            *(uint4*)(&sA[rowT * LDA + c16 * 8]) = pk;
            *(bf16x8*)(&sB[rowT * LDA + c16 * 8]) =
                *(const bf16x8*)(BT + (size_t)(ncol0 + rowT) * K + k0 + c16 * 8);
        }
        __syncthreads();
        bf16x8 af[2], bfr[2];
#pragma unroll
        for (int t = 0; t < 2; t++) {
            af[t]  = *(const bf16x8*)(&sA[(wm + t * 16 + lrow) * LDA + lk]);
            bfr[t] = *(const bf16x8*)(&sB[(wn + t * 16 + lrow) * LDA + lk]);
        }
#pragma unroll
        for (int tm = 0; tm < 2; tm++)
#pragma unroll
            for (int tn = 0; tn < 2; tn++)
                acc[tm][tn] = __builtin_amdgcn_mfma_f32_16x16x32_bf16(af[tm], bfr[tn], acc[tm][tn], 0, 0, 0);
        __syncthreads();
    }

    int lcol = lane & 15, lr4 = (lane >> 4) * 4;
#pragma unroll
    for (int tm = 0; tm < 2; tm++) {
#pragma unroll
        for (int i = 0; i < 4; i++) {
            int row = m0 + wm + tm * 16 + lr4 + i;
            if (row < M) {
#pragma unroll
                for (int tn = 0; tn < 2; tn++) {
                    int col = ncol0 + wn + tn * 16 + lcol;
                    float v = acc[tm][tn][i] + bias[col];
                    if (Cf) Cf[(size_t)row * Nout + col] = v;
                    else    Cb[(size_t)row * Nout + col] = __float2bfloat16(v);
                }
            }
        }
    }
}

// ---------------- deform core: softmax+loc fused, 4 queries/block, 8 lanes/(q,h) ----------------
__global__ __launch_bounds__(256) void deform(const __hip_bfloat16* __restrict__ value,
                                              const float* __restrict__ locraw,
                                              const float* __restrict__ logits,
                                              const float* __restrict__ refp,
                                              __hip_bfloat16* __restrict__ out) {
    __shared__ float wS[4][8][16][4];
    __shared__ int   aS[4][8][16][4];
    int tid = threadIdx.x;
    int q0 = blockIdx.x * 4;

    {   // phase 1
        int sub = tid >> 6, h = (tid >> 3) & 7, t8 = tid & 7;
        int q = q0 + sub;
        const float* lg = logits + q * 128 + h * 16;
        float l0 = lg[t8], l1 = lg[t8 + 8];
        float mx = fmaxf(l0, l1);
#pragma unroll
        for (int m = 1; m < 8; m <<= 1) mx = fmaxf(mx, __shfl_xor(mx, m, 64));
        float e0 = __expf(l0 - mx), e1 = __expf(l1 - mx);
        float s = e0 + e1;
#pragma unroll
        for (int m = 1; m < 8; m <<= 1) s += __shfl_xor(s, m, 64);
        float inv = 1.f / s;

        const int starts[4] = {0, 6400, 8000, 8400};
#pragma unroll
        for (int j = 0; j < 2; j++) {
            int pp = t8 + 8 * j;
            float a = (j ? e1 : e0) * inv;
            int l = pp >> 2;
            int Wl = 80 >> l;
            float nv = (float)Wl;
            float rx = refp[q * 8 + l * 2 + 0];
            float ry = refp[q * 8 + l * 2 + 1];
            float lx = rx + locraw[q * 256 + h * 32 + pp * 2 + 0] / nv;
            float ly = ry + locraw[q * 256 + h * 32 + pp * 2 + 1] / nv;
            float x = lx * nv - 0.5f;
            float y = ly * nv - 0.5f;
            float x0f = floorf(x), y0f = floorf(y);
            float fx = x - x0f, fy = y - y0f;
            int x0 = (int)x0f, y0 = (int)y0f;
            float wts[4] = {(1.f - fx) * (1.f - fy), fx * (1.f - fy),
                            (1.f - fx) * fy,         fx * fy};
            int st = starts[l];
#pragma unroll
            for (int t = 0; t < 4; t++) {
                int xi = x0 + (t & 1), yi = y0 + (t >> 1);
                bool valid = (xi >= 0) & (xi < Wl) & (yi >= 0) & (yi < Wl);
                int xc = min(max(xi, 0), Wl - 1), yc = min(max(yi, 0), Wl - 1);
                wS[sub][h][pp][t] = valid ? wts[t] * a : 0.f;
                aS[sub][h][pp][t] = (st + yc * Wl + xc) * 512 + h * 64;
            }
        }
    }
    __syncthreads();

    // phase 2: tid = sub*64 + h*8 + l8
    int sub = tid >> 6, h = (tid >> 3) & 7, l8 = tid & 7;
    int q = q0 + sub;
    const char* vb = (const char*)value;
    int lo = l8 * 8;
    float a0 = 0.f, a1 = 0.f, a2 = 0.f, a3 = 0.f;
#pragma unroll
    for (int p = 0; p < 16; p++) {
        floatx4 w = *(const floatx4*)&wS[sub][h][p][0];
        int4 av = *(const int4*)&aS[sub][h][p][0];
#pragma unroll
        for (int t = 0; t < 4; t++) {
            int ad = (t == 0) ? av.x : (t == 1) ? av.y : (t == 2) ? av.z : av.w;
            uint2 u = *(const uint2*)(vb + ad + lo);
            float wt = w[t];
            a0 += wt * __uint_as_float(u.x << 16);
            a1 += wt * __uint_as_float(u.x & 0xffff0000u);
            a2 += wt * __uint_as_float(u.y << 16);
            a3 += wt * __uint_as_float(u.y & 0xffff0000u);
        }
    }
    uint2 o;
    o.x = bpack(a0, a1);
    o.y = bpack(a2, a3);
    *(uint2*)((char*)out + q * 512 + h * 64 + l8 * 8) = o;
}

// ---------------- GEMM (N=256) + bias + residual + LayerNorm fused; 512 threads ----------------
// BM=32, BN=256 (full row per block). 8 waves, each owns 32 N-cols.
__global__ __launch_bounds__(512) void gemm_ln(
    const __hip_bfloat16* __restrict__ A, const __hip_bfloat16* __restrict__ BT,
    const float* __restrict__ bias, const float* __restrict__ resid,
    const float* __restrict__ g, const float* __restrict__ be,
    float* __restrict__ outf, __hip_bfloat16* __restrict__ outb,
    int M, int K) {
    constexpr int BM = 32, BK = 32, LDA = BK + 8;
    __shared__ __align__(16) __hip_bfloat16 sA[BM * LDA];
    __shared__ __align__(16) __hip_bfloat16 sB[256 * LDA];
    __shared__ float psum[8][32], psq[8][32], mS[32], rS[32];

    int tid = threadIdx.x;
    int wave = tid >> 6, lane = tid & 63;
    int m0 = blockIdx.x * BM;

    floatx4 acc[2][2];
#pragma unroll
    for (int i = 0; i < 2; i++)
#pragma unroll
        for (int j = 0; j < 2; j++)
#pragma unroll
            for (int e = 0; e < 4; e++) acc[i][j][e] = 0.f;

    int rowT = tid >> 2, c16 = tid & 3;     // rowT 0..127
    int lrow = lane & 15, lk = (lane >> 4) * 8;

    for (int k0 = 0; k0 < K; k0 += BK) {
        if (tid < 128) {
            int grow = m0 + rowT; if (grow >= M) grow = M - 1;
            *(bf16x8*)(&sA[rowT * LDA + c16 * 8]) =
                *(const bf16x8*)(A + (size_t)grow * K + k0 + c16 * 8);
        }
#pragma unroll
        for (int r = 0; r < 2; r++) {
            int row = r * 128 + rowT;
            *(bf16x8*)(&sB[row * LDA + c16 * 8]) =
                *(const bf16x8*)(BT + (size_t)row * K + k0 + c16 * 8);
        }
        __syncthreads();
        bf16x8 af[2], bfr[2];
#pragma unroll
        for (int tm = 0; tm < 2; tm++)
            af[tm] = *(const bf16x8*)(&sA[(tm * 16 + lrow) * LDA + lk]);
#pragma unroll
        for (int tn = 0; tn < 2; tn++)
            bfr[tn] = *(const bf16x8*)(&sB[(wave * 32 + tn * 16 + lrow) * LDA + lk]);
#pragma unroll
        for (int tm = 0; tm < 2; tm++)
#pragma unroll
            for (int tn = 0; tn < 2; tn++)
                acc[tm][tn] = __builtin_amdgcn_mfma_f32_16x16x32_bf16(af[tm], bfr[tn], acc[tm][tn], 0, 0, 0);
        __syncthreads();
    }

    int lcol = lane & 15, quad = lane >> 4;
    float v[2][2][4];
#pragma unroll
    for (int tm = 0; tm < 2; tm++) {
#pragma unroll
        for (int i = 0; i < 4; i++) {
            int row = tm * 16 + quad * 4 + i;
            int grow = m0 + row; if (grow >= M) grow = M - 1;
#pragma unroll
            for (int tn = 0; tn < 2; tn++) {
                int col = wave * 32 + tn * 16 + lcol;
                v[tm][tn][i] = acc[tm][tn][i] + bias[col] + resid[(size_t)grow * 256 + col];
            }
        }
    }

#pragma unroll
    for (int tm = 0; tm < 2; tm++) {
#pragma unroll
        for (int i = 0; i < 4; i++) {
            float s = 0.f, s2 = 0.f;
#pragma unroll
            for (int tn = 0; tn < 2; tn++) { float x = v[tm][tn][i]; s += x; s2 += x * x; }
#pragma unroll
            for (int m = 1; m < 16; m <<= 1) {
                s  += __shfl_xor(s, m, 64);
                s2 += __shfl_xor(s2, m, 64);
            }
            if (lcol == 0) {
                int row = tm * 16 + quad * 4 + i;
                psum[wave][row] = s;
                psq[wave][row]  = s2;
            }
        }
    }
    __syncthreads();
    if (tid < 32) {
        float s = 0.f, s2 = 0.f;
#pragma unroll
        for (int w = 0; w < 8; w++) { s += psum[w][tid]; s2 += psq[w][tid]; }
        float m = s * (1.f / 256.f);
        float var = fmaxf(s2 * (1.f / 256.f) - m * m, 0.f);
        mS[tid] = m;
        rS[tid] = rsqrtf(var + 1e-5f);
    }
    __syncthreads();

#pragma unroll
    for (int tm = 0; tm < 2; tm++) {
#pragma unroll
        for (int i = 0; i < 4; i++) {
            int row = tm * 16 + quad * 4 + i;
            int grow = m0 + row;
            if (grow < M) {
                float m = mS[row], r = rS[row];
#pragma unroll
                for (int tn = 0; tn < 2; tn++) {
                    int col = wave * 32 + tn * 16 + lcol;
                    float o = (v[tm][tn][i] - m) * r * g[col] + be[col];
                    outf[(size_t)grow * 256 + col] = o;
                    if (outb) outb[(size_t)grow * 256 + col] = __float2bfloat16(o);
                }
            }
        }
    }
}

extern "C" void kernel_launch(void* const* d_in, const int* in_sizes, int n_in,
                              void* d_out, int out_size, void* d_ws, size_t ws_size,
                              hipStream_t stream) {
    const float* src  = (const float*)d_in[0];
    const float* pos  = (const float*)d_in[1];
    const float* refp = (const float*)d_in[2];
    const float* Wo   = (const float*)d_in[6];
    const float* bo   = (const float*)d_in[7];
    const float* Wa   = (const float*)d_in[8];
    const float* ba   = (const float*)d_in[9];
    const float* Wv   = (const float*)d_in[10];
    const float* bv   = (const float*)d_in[11];
    const float* Wout = (const float*)d_in[12];
    const float* bout = (const float*)d_in[13];
    const float* W1   = (const float*)d_in[14];
    const float* b1   = (const float*)d_in[15];
    const float* W2   = (const float*)d_in[16];
    const float* b2   = (const float*)d_in[17];
    const float* g1   = (const float*)d_in[18];
    const float* be1  = (const float*)d_in[19];
    const float* g2   = (const float*)d_in[20];
    const float* be2  = (const float*)d_in[21];
    float* out = (float*)d_out;
    char* ws = (char*)d_ws;

    // ---- workspace layout (bytes) ----
    __hip_bfloat16* WoT   = (__hip_bfloat16*)(ws + 0);         //  131072
    __hip_bfloat16* WaT   = (__hip_bfloat16*)(ws + 131072);    //   65536
    __hip_bfloat16* WvT   = (__hip_bfloat16*)(ws + 196608);    //  131072
    __hip_bfloat16* WoutT = (__hip_bfloat16*)(ws + 327680);    //  131072
    __hip_bfloat16* W1T   = (__hip_bfloat16*)(ws + 458752);    //  524288
    __hip_bfloat16* W2T   = (__hip_bfloat16*)(ws + 983040);    //  524288
    float*          locb  = (float*)(ws + 1507328);            // 8704000
    float*          attnb = (float*)(ws + 10211328);           // 4352000
    __hip_bfloat16* valb  = (__hip_bfloat16*)(ws + 14563328);  // 4352000
    __hip_bfloat16* aob   = (__hip_bfloat16*)(ws + 18915328);  // 4352000
    float*          x1    = (float*)(ws + 23267328);           // 8704000
    __hip_bfloat16* x1b   = (__hip_bfloat16*)(ws + 31971328);  // 4352000
    __hip_bfloat16* hb    = (__hip_bfloat16*)(ws + 36323328);  // 17408000  (end ~53.7 MB)

    transpose_all<<<736, 256, 0, stream>>>(Wo, Wa, Wv, Wout, W1, W2,
                                           WoT, WaT, WvT, WoutT, W1T, W2T);

    proj_fused<<<dim3(10, 133), 256, 0, stream>>>(src, pos, WoT, WaT, WvT, bo, ba, bv,
                                                  locb, attnb, valb, LTOT);

    deform<<<2125, 256, 0, stream>>>(valb, locb, attnb, refp, aob);

    gemm_ln<<<266, 512, 0, stream>>>(aob, WoutT, bout, src, g1, be1, x1, x1b, LTOT, 256);
    gemm_mfma<128, 128><<<dim3(8, 67), 256, 0, stream>>>(x1b, W1T, b1, nullptr, hb, LTOT, 1024, 256, 1);
    gemm_ln<<<266, 512, 0, stream>>>(hb, W2T, b2, x1, g2, be2, out, nullptr, LTOT, 1024);
}